// Round 1
// baseline (942.520 us; speedup 1.0000x reference)
//
#include <hip/hip_runtime.h>
#include <math.h>

#define D 256
#define HN 4
#define HT 4

__device__ __forceinline__ float lrelu(float x){ return x > 0.f ? x : 0.01f*x; }
__device__ __forceinline__ float gelu_exact(float x){ return 0.5f*x*(1.f+erff(x*0.70710678118654752f)); }

__device__ __forceinline__ float wred_sum(float v){
#pragma unroll
  for (int o = 32; o > 0; o >>= 1) v += __shfl_xor(v, o);
  return v;
}
__device__ __forceinline__ float wred_max(float v){
#pragma unroll
  for (int o = 32; o > 0; o >>= 1) v = fmaxf(v, __shfl_xor(v, o));
  return v;
}
__device__ __forceinline__ float4 wred_sum4(float4 v){
  v.x = wred_sum(v.x); v.y = wred_sum(v.y); v.z = wred_sum(v.z); v.w = wred_sum(v.w);
  return v;
}
__device__ __forceinline__ float4 wred_max4(float4 v){
  v.x = wred_max(v.x); v.y = wred_max(v.y); v.z = wred_max(v.z); v.w = wred_max(v.w);
  return v;
}

#define ACC4(p, s, w) do { (p).x = fmaf((s),(w).x,(p).x); (p).y = fmaf((s),(w).y,(p).y); \
                           (p).z = fmaf((s),(w).z,(p).z); (p).w = fmaf((s),(w).w,(p).w); } while(0)

// ---------------------------------------------------------------------------
// C[M x 256] = A[M x 256] @ W[256 x 256] + bias   (fp32, vector ALU)
// 64x64 tile per block, 256 threads, 4x4 micro-tile per thread, BK=16.
// ---------------------------------------------------------------------------
__global__ __launch_bounds__(256) void gemm_bias_256(
    const float* __restrict__ A, const float* __restrict__ W,
    const float* __restrict__ bias, float* __restrict__ C, int M)
{
  __shared__ float At[16][64];   // A transposed tile: At[k][m]
  __shared__ float Wt[16][68];   // W tile, padded row
  const int tid = threadIdx.x;
  const int bm = blockIdx.x * 64;
  const int bn = blockIdx.y * 64;
  const int tx = tid & 15, ty = tid >> 4;
  float acc[4][4] = {{0.f}};
  const int lm = tid >> 2;          // 0..63 A row
  const int lk = (tid & 3) << 2;    // 0,4,8,12
  const int wk = tid >> 4;          // 0..15 W row
  const int wn = (tid & 15) << 2;   // 0..60

  for (int k0 = 0; k0 < 256; k0 += 16) {
    float4 a4 = make_float4(0.f,0.f,0.f,0.f);
    int arow = bm + lm;
    if (arow < M) a4 = *(const float4*)(A + (size_t)arow*256 + k0 + lk);
    At[lk+0][lm] = a4.x; At[lk+1][lm] = a4.y; At[lk+2][lm] = a4.z; At[lk+3][lm] = a4.w;
    float4 w4 = *(const float4*)(W + (size_t)(k0+wk)*256 + bn + wn);
    *(float4*)&Wt[wk][wn] = w4;
    __syncthreads();
#pragma unroll
    for (int k = 0; k < 16; ++k) {
      float4 av = *(float4*)&At[k][ty<<2];
      float4 wv = *(float4*)&Wt[k][tx<<2];
      acc[0][0]=fmaf(av.x,wv.x,acc[0][0]); acc[0][1]=fmaf(av.x,wv.y,acc[0][1]);
      acc[0][2]=fmaf(av.x,wv.z,acc[0][2]); acc[0][3]=fmaf(av.x,wv.w,acc[0][3]);
      acc[1][0]=fmaf(av.y,wv.x,acc[1][0]); acc[1][1]=fmaf(av.y,wv.y,acc[1][1]);
      acc[1][2]=fmaf(av.y,wv.z,acc[1][2]); acc[1][3]=fmaf(av.y,wv.w,acc[1][3]);
      acc[2][0]=fmaf(av.z,wv.x,acc[2][0]); acc[2][1]=fmaf(av.z,wv.y,acc[2][1]);
      acc[2][2]=fmaf(av.z,wv.z,acc[2][2]); acc[2][3]=fmaf(av.z,wv.w,acc[2][3]);
      acc[3][0]=fmaf(av.w,wv.x,acc[3][0]); acc[3][1]=fmaf(av.w,wv.y,acc[3][1]);
      acc[3][2]=fmaf(av.w,wv.z,acc[3][2]); acc[3][3]=fmaf(av.w,wv.w,acc[3][3]);
    }
    __syncthreads();
  }
  float4 b4 = *(const float4*)(bias + bn + (tx<<2));
#pragma unroll
  for (int i = 0; i < 4; ++i) {
    int row = bm + (ty<<2) + i;
    if (row < M) {
      float4 o = make_float4(acc[i][0]+b4.x, acc[i][1]+b4.y, acc[i][2]+b4.z, acc[i][3]+b4.w);
      *(float4*)(C + (size_t)row*256 + bn + (tx<<2)) = o;
    }
  }
}

// ---------------------------------------------------------------------------
// Per-node attention projections: a_src_r = hs_r @ srcA_W[r] + b ; a_dst_r = hd @ dstA_W[r] + b
// One wave per node.
// ---------------------------------------------------------------------------
__global__ __launch_bounds__(256) void attn_vec_kernel(
    const float* __restrict__ hs0, const float* __restrict__ hs1,
    const float* __restrict__ hd,
    const float* __restrict__ srcA_W, const float* __restrict__ srcA_b,
    const float* __restrict__ dstA_W, const float* __restrict__ dstA_b,
    float* __restrict__ as0, float* __restrict__ as1,
    float* __restrict__ ad0, float* __restrict__ ad1, int N)
{
  int n = blockIdx.x*4 + (threadIdx.x >> 6);
  if (n >= N) return;
  int lane = threadIdx.x & 63;
  int d0 = lane << 2;
  const float4* Ws = (const float4*)srcA_W;   // [r*256 + d]
  const float4* Wd = (const float4*)dstA_W;
  float4 r0 = ((const float4*)hs0)[(size_t)n*64 + lane];
  float4 r1 = ((const float4*)hs1)[(size_t)n*64 + lane];
  float4 rd = ((const float4*)hd )[(size_t)n*64 + lane];
  float4 p0 = make_float4(0,0,0,0), p1 = make_float4(0,0,0,0);
  float4 q0 = make_float4(0,0,0,0), q1 = make_float4(0,0,0,0);
  float4 w;
  w = Ws[d0+0]; ACC4(p0, r0.x, w);
  w = Ws[d0+1]; ACC4(p0, r0.y, w);
  w = Ws[d0+2]; ACC4(p0, r0.z, w);
  w = Ws[d0+3]; ACC4(p0, r0.w, w);
  w = Ws[256+d0+0]; ACC4(p1, r1.x, w);
  w = Ws[256+d0+1]; ACC4(p1, r1.y, w);
  w = Ws[256+d0+2]; ACC4(p1, r1.z, w);
  w = Ws[256+d0+3]; ACC4(p1, r1.w, w);
  w = Wd[d0+0]; ACC4(q0, rd.x, w);
  w = Wd[d0+1]; ACC4(q0, rd.y, w);
  w = Wd[d0+2]; ACC4(q0, rd.z, w);
  w = Wd[d0+3]; ACC4(q0, rd.w, w);
  w = Wd[256+d0+0]; ACC4(q1, rd.x, w);
  w = Wd[256+d0+1]; ACC4(q1, rd.y, w);
  w = Wd[256+d0+2]; ACC4(q1, rd.z, w);
  w = Wd[256+d0+3]; ACC4(q1, rd.w, w);
  p0 = wred_sum4(p0); p1 = wred_sum4(p1); q0 = wred_sum4(q0); q1 = wred_sum4(q1);
  if (lane == 0) {
    float4 b;
    b = *(const float4*)(srcA_b + 0);
    ((float4*)as0)[n] = make_float4(p0.x+b.x, p0.y+b.y, p0.z+b.z, p0.w+b.w);
    b = *(const float4*)(srcA_b + 4);
    ((float4*)as1)[n] = make_float4(p1.x+b.x, p1.y+b.y, p1.z+b.z, p1.w+b.w);
    b = *(const float4*)(dstA_b + 0);
    ((float4*)ad0)[n] = make_float4(q0.x+b.x, q0.y+b.y, q0.z+b.z, q0.w+b.w);
    b = *(const float4*)(dstA_b + 4);
    ((float4*)ad1)[n] = make_float4(q1.x+b.x, q1.y+b.y, q1.z+b.z, q1.w+b.w);
  }
}

// ---------------------------------------------------------------------------
// rel attention (node-invariant): rel[r][h] = softmax_r(lrelu(rel_emb[r]·relA_W[r][:,h] + b)),
// stored pre-scaled by (1-ALPHA)=0.5
// ---------------------------------------------------------------------------
__global__ void rel_kernel(const float* __restrict__ rel_emb, const float* __restrict__ relA_W,
                           const float* __restrict__ relA_b, float* __restrict__ rel_out)
{
  int t = threadIdx.x;
  if (t < 8) {
    int r = t >> 2, h = t & 3;
    float s = relA_b[r*4+h];
    for (int d = 0; d < 256; ++d)
      s = fmaf(rel_emb[r*256+d], relA_W[(size_t)(r*256+d)*4+h], s);
    s = lrelu(s);
    float other = __shfl_xor(s, 4);
    float mm = fmaxf(s, other);
    float e  = expf(s - mm), eo = expf(other - mm);
    rel_out[r*4+h] = 0.5f * e / (e + eo);
  }
}

// ---------------------------------------------------------------------------
// CSR build helpers
// ---------------------------------------------------------------------------
__global__ void zero_int(int* p, int n){
  int i = blockIdx.x*blockDim.x + threadIdx.x;
  if (i < n) p[i] = 0;
}

__global__ void hist_kernel(const int* __restrict__ dst0, const int* __restrict__ dst1,
                            int* c0, int* c1, int E){
  int e = blockIdx.x*256 + threadIdx.x;
  if (e < E) { atomicAdd(&c0[dst0[e]], 1); atomicAdd(&c1[dst1[e]], 1); }
}

__global__ __launch_bounds__(1024) void scan1(const int* __restrict__ cnt, int* __restrict__ excl,
                                              int* __restrict__ part, int n){
  __shared__ int sm[1024];
  int tid = threadIdx.x;
  int gid = blockIdx.x*1024 + tid;
  int v = (gid < n) ? cnt[gid] : 0;
  sm[tid] = v; __syncthreads();
  for (int off = 1; off < 1024; off <<= 1){
    int t = sm[tid];
    if (tid >= off) t += sm[tid-off];
    __syncthreads();
    sm[tid] = t; __syncthreads();
  }
  if (gid < n) excl[gid] = sm[tid] - v;
  if (tid == 1023) part[blockIdx.x] = sm[1023];
}

__global__ void scan2(int* part, int nchunk, int* total_out){
  if (threadIdx.x == 0 && blockIdx.x == 0){
    int run = 0;
    for (int i = 0; i < nchunk; ++i){ int t = part[i]; part[i] = run; run += t; }
    *total_out = run;
  }
}

__global__ __launch_bounds__(1024) void scan3(int* __restrict__ rp, int* __restrict__ cur,
                                              const int* __restrict__ part, int n){
  int gid = blockIdx.x*1024 + threadIdx.x;
  if (gid < n){ int v = rp[gid] + part[blockIdx.x]; rp[gid] = v; cur[gid] = v; }
}

__global__ void scatter_kernel(const int* __restrict__ src0, const int* __restrict__ dst0,
                               int* cur0, int* __restrict__ csr0,
                               const int* __restrict__ src1, const int* __restrict__ dst1,
                               int* cur1, int* __restrict__ csr1, int E){
  int e = blockIdx.x*256 + threadIdx.x;
  if (e < E){
    int p = atomicAdd(&cur0[dst0[e]], 1); csr0[p] = src0[e];
    p = atomicAdd(&cur1[dst1[e]], 1); csr1[p] = src1[e];
  }
}

// ---------------------------------------------------------------------------
// Per-dst edge-softmax + weighted message aggregation. One wave per dst node.
// blockIdx.y selects relation.
// ---------------------------------------------------------------------------
__global__ __launch_bounds__(256) void aggregate_kernel(
    const int* __restrict__ rp0, const int* __restrict__ csr0,
    const float* __restrict__ as0, const float* __restrict__ ad0,
    const float* __restrict__ hs0, float* __restrict__ z0,
    const int* __restrict__ rp1, const int* __restrict__ csr1,
    const float* __restrict__ as1, const float* __restrict__ ad1,
    const float* __restrict__ hs1, float* __restrict__ z1, int N)
{
  int n = blockIdx.x*4 + (threadIdx.x >> 6);
  if (n >= N) return;
  int lane = threadIdx.x & 63;
  const int* rp; const int* csr; const float* as; const float* ad; const float* hs; float* z;
  if (blockIdx.y == 0){ rp=rp0; csr=csr0; as=as0; ad=ad0; hs=hs0; z=z0; }
  else               { rp=rp1; csr=csr1; as=as1; ad=ad1; hs=hs1; z=z1; }
  int start = rp[n];
  int cnt   = rp[n+1] - start;
  float4* zout = (float4*)z;
  if (cnt == 0){ zout[(size_t)n*64 + lane] = make_float4(0,0,0,0); return; }
  float4 adv = *(const float4*)(ad + (size_t)n*4);
  // pass 1: per-head max over in-edges
  float4 m = make_float4(-INFINITY,-INFINITY,-INFINITY,-INFINITY);
  for (int i = lane; i < cnt; i += 64){
    int s = csr[start+i];
    float4 a = *(const float4*)(as + (size_t)s*4);
    a.x = lrelu(a.x+adv.x); a.y = lrelu(a.y+adv.y); a.z = lrelu(a.z+adv.z); a.w = lrelu(a.w+adv.w);
    m.x = fmaxf(m.x,a.x); m.y = fmaxf(m.y,a.y); m.z = fmaxf(m.z,a.z); m.w = fmaxf(m.w,a.w);
  }
  m = wred_max4(m);
  // pass 2: denominators
  float4 ssum = make_float4(0,0,0,0);
  for (int i = lane; i < cnt; i += 64){
    int s = csr[start+i];
    float4 a = *(const float4*)(as + (size_t)s*4);
    ssum.x += expf(lrelu(a.x+adv.x) - m.x);
    ssum.y += expf(lrelu(a.y+adv.y) - m.y);
    ssum.z += expf(lrelu(a.z+adv.z) - m.z);
    ssum.w += expf(lrelu(a.w+adv.w) - m.w);
  }
  ssum = wred_sum4(ssum);
  // pass 3: weighted row accumulation (lane covers d = lane*4..+3, head = lane>>4)
  int h = lane >> 4;
  float mh  = h==0 ? m.x    : h==1 ? m.y    : h==2 ? m.z    : m.w;
  float sh  = h==0 ? ssum.x : h==1 ? ssum.y : h==2 ? ssum.z : ssum.w;
  float adh = h==0 ? adv.x  : h==1 ? adv.y  : h==2 ? adv.z  : adv.w;
  float4 acc = make_float4(0,0,0,0);
  const float4* hsv = (const float4*)hs;
  for (int i = 0; i < cnt; ++i){
    int s = csr[start+i];
    float wgt = expf(lrelu(as[(size_t)s*4+h] + adh) - mh) / sh;
    float4 hv = hsv[(size_t)s*64 + lane];
    acc.x = fmaf(hv.x, wgt, acc.x); acc.y = fmaf(hv.y, wgt, acc.y);
    acc.z = fmaf(hv.z, wgt, acc.z); acc.w = fmaf(hv.w, wgt, acc.w);
  }
  zout[(size_t)n*64 + lane] = acc;
}

// ---------------------------------------------------------------------------
// Final fusion for node type A: semantic attention + relation attention + gelu + normalize
// One wave per node. hd_in == outA region (read raw z_dst, then overwrite with out_A).
// ---------------------------------------------------------------------------
__device__ __forceinline__ void sm2(float s0, float s1, float r0, float r1, float& o0, float& o1){
  float mm = fmaxf(s0, s1);
  float e0 = expf(s0-mm), e1 = expf(s1-mm);
  float inv = 1.f/(e0+e1);
  o0 = fmaf(0.5f*e0, inv, r0);
  o1 = fmaf(0.5f*e1, inv, r1);
}

__global__ __launch_bounds__(256) void fusionA_kernel(
    const float* __restrict__ z0, const float* __restrict__ z1,
    float* __restrict__ hd_io, const float* __restrict__ hA,
    const float* __restrict__ semS_W, const float* __restrict__ semS_b,
    const float* __restrict__ semD_W, const float* __restrict__ semD_b,
    const float* __restrict__ relw, int N)
{
  int n = blockIdx.x*4 + (threadIdx.x >> 6);
  if (n >= N) return;
  int lane = threadIdx.x & 63;
  int d0 = lane << 2;
  float4 a0 = ((const float4*)z0)[(size_t)n*64 + lane];
  float4 a1 = ((const float4*)z1)[(size_t)n*64 + lane];
  float4 ad = ((float4*)hd_io)[(size_t)n*64 + lane];
  float4 ha = ((const float4*)hA)[(size_t)n*64 + lane];
  // norms of z0, z1, z_dst
  float nz0 = wred_sum(a0.x*a0.x + a0.y*a0.y + a0.z*a0.z + a0.w*a0.w);
  float nz1 = wred_sum(a1.x*a1.x + a1.y*a1.y + a1.z*a1.z + a1.w*a1.w);
  float nzd = wred_sum(ad.x*ad.x + ad.y*ad.y + ad.z*ad.z + ad.w*ad.w);
  float i0 = 1.f / fmaxf(sqrtf(nz0), 1e-9f);
  float i1 = 1.f / fmaxf(sqrtf(nz1), 1e-9f);
  float idn = 1.f / fmaxf(sqrtf(nzd), 1e-9f);
  // 16 dots: z_r·semS_W[r][:,h], z_dst·semD_W[r][:,h]
  const float4* WS = (const float4*)semS_W;
  const float4* WD = (const float4*)semD_W;
  float4 p0 = make_float4(0,0,0,0), p1 = make_float4(0,0,0,0);
  float4 q0 = make_float4(0,0,0,0), q1 = make_float4(0,0,0,0);
  float4 w;
  w = WS[d0+0]; ACC4(p0, a0.x, w);
  w = WS[d0+1]; ACC4(p0, a0.y, w);
  w = WS[d0+2]; ACC4(p0, a0.z, w);
  w = WS[d0+3]; ACC4(p0, a0.w, w);
  w = WS[256+d0+0]; ACC4(p1, a1.x, w);
  w = WS[256+d0+1]; ACC4(p1, a1.y, w);
  w = WS[256+d0+2]; ACC4(p1, a1.z, w);
  w = WS[256+d0+3]; ACC4(p1, a1.w, w);
  w = WD[d0+0]; ACC4(q0, ad.x, w);
  w = WD[d0+1]; ACC4(q0, ad.y, w);
  w = WD[d0+2]; ACC4(q0, ad.z, w);
  w = WD[d0+3]; ACC4(q0, ad.w, w);
  w = WD[256+d0+0]; ACC4(q1, ad.x, w);
  w = WD[256+d0+1]; ACC4(q1, ad.y, w);
  w = WD[256+d0+2]; ACC4(q1, ad.z, w);
  w = WD[256+d0+3]; ACC4(q1, ad.w, w);
  p0 = wred_sum4(p0); p1 = wred_sum4(p1); q0 = wred_sum4(q0); q1 = wred_sum4(q1);
  float4 sb0 = *(const float4*)(semS_b + 0);
  float4 sb1 = *(const float4*)(semS_b + 4);
  float4 db0 = *(const float4*)(semD_b + 0);
  float4 db1 = *(const float4*)(semD_b + 4);
  float4 s0, s1;
  s0.x = lrelu(p0.x*i0 + sb0.x + q0.x*idn + db0.x);
  s0.y = lrelu(p0.y*i0 + sb0.y + q0.y*idn + db0.y);
  s0.z = lrelu(p0.z*i0 + sb0.z + q0.z*idn + db0.z);
  s0.w = lrelu(p0.w*i0 + sb0.w + q0.w*idn + db0.w);
  s1.x = lrelu(p1.x*i1 + sb1.x + q1.x*idn + db1.x);
  s1.y = lrelu(p1.y*i1 + sb1.y + q1.y*idn + db1.y);
  s1.z = lrelu(p1.z*i1 + sb1.z + q1.z*idn + db1.z);
  s1.w = lrelu(p1.w*i1 + sb1.w + q1.w*idn + db1.w);
  float4 at0, at1;
  sm2(s0.x, s1.x, relw[0], relw[4], at0.x, at1.x);
  sm2(s0.y, s1.y, relw[1], relw[5], at0.y, at1.y);
  sm2(s0.z, s1.z, relw[2], relw[6], at0.z, at1.z);
  sm2(s0.w, s1.w, relw[3], relw[7], at0.w, at1.w);
  int h = lane >> 4;
  float w0 = h==0 ? at0.x : h==1 ? at0.y : h==2 ? at0.z : at0.w;
  float w1 = h==0 ? at1.x : h==1 ? at1.y : h==2 ? at1.z : at1.w;
  float4 x;
  x.x = fmaf(a0.x, w0, fmaf(a1.x, w1, ha.x));
  x.y = fmaf(a0.y, w0, fmaf(a1.y, w1, ha.y));
  x.z = fmaf(a0.z, w0, fmaf(a1.z, w1, ha.z));
  x.w = fmaf(a0.w, w0, fmaf(a1.w, w1, ha.w));
  float4 g;
  g.x = gelu_exact(x.x); g.y = gelu_exact(x.y); g.z = gelu_exact(x.z); g.w = gelu_exact(x.w);
  float ng = wred_sum(g.x*g.x + g.y*g.y + g.z*g.z + g.w*g.w);
  float inv = 1.f / fmaxf(sqrtf(ng), 1e-9f);
  g.x *= inv; g.y *= inv; g.z *= inv; g.w *= inv;
  ((float4*)hd_io)[(size_t)n*64 + lane] = g;
}

// Node type B fallback: out_B = normalize(gelu(nb + h_B)); nb lives in outB region.
__global__ __launch_bounds__(256) void fusionB_kernel(float* __restrict__ outB,
                                                      const float* __restrict__ hB, int N)
{
  int n = blockIdx.x*4 + (threadIdx.x >> 6);
  if (n >= N) return;
  int lane = threadIdx.x & 63;
  float4 x = ((float4*)outB)[(size_t)n*64 + lane];
  float4 b = ((const float4*)hB)[(size_t)n*64 + lane];
  x.x += b.x; x.y += b.y; x.z += b.z; x.w += b.w;
  float4 g;
  g.x = gelu_exact(x.x); g.y = gelu_exact(x.y); g.z = gelu_exact(x.z); g.w = gelu_exact(x.w);
  float ng = wred_sum(g.x*g.x + g.y*g.y + g.z*g.z + g.w*g.w);
  float inv = 1.f / fmaxf(sqrtf(ng), 1e-9f);
  g.x *= inv; g.y *= inv; g.z *= inv; g.w *= inv;
  ((float4*)outB)[(size_t)n*64 + lane] = g;
}

// ---------------------------------------------------------------------------
extern "C" void kernel_launch(void* const* d_in, const int* in_sizes, int n_in,
                              void* d_out, int out_size, void* d_ws, size_t ws_size,
                              hipStream_t stream)
{
  const float* hA     = (const float*)d_in[0];
  const float* hB     = (const float*)d_in[1];
  const int*   src0   = (const int*)d_in[2];
  const int*   dst0   = (const int*)d_in[3];
  const int*   src1   = (const int*)d_in[4];
  const int*   dst1   = (const int*)d_in[5];
  const float* node_W = (const float*)d_in[6];
  const float* node_b = (const float*)d_in[7];
  const float* edge_W = (const float*)d_in[8];
  const float* edge_b = (const float*)d_in[9];
  const float* srcA_W = (const float*)d_in[10];
  const float* srcA_b = (const float*)d_in[11];
  const float* dstA_W = (const float*)d_in[12];
  const float* dstA_b = (const float*)d_in[13];
  const float* semS_W = (const float*)d_in[14];
  const float* semS_b = (const float*)d_in[15];
  const float* semD_W = (const float*)d_in[16];
  const float* semD_b = (const float*)d_in[17];
  const float* relA_W = (const float*)d_in[18];
  const float* relA_b = (const float*)d_in[19];
  const float* rel_emb= (const float*)d_in[20];

  const int N = in_sizes[0] / D;
  const int E = in_sizes[2];

  float* out  = (float*)d_out;
  float* outA = out;                    // scratch for hd (=z_dst), then final out_A
  float* outB = out + (size_t)N*D;      // scratch for nb, then final out_B

  float* w = (float*)d_ws;
  float* hs0 = w; w += (size_t)N*D;
  float* hs1 = w; w += (size_t)N*D;
  float* z0  = w; w += (size_t)N*D;
  float* z1  = w; w += (size_t)N*D;
  float* as0 = w; w += (size_t)N*HN;
  float* as1 = w; w += (size_t)N*HN;
  float* ad0 = w; w += (size_t)N*HN;
  float* ad1 = w; w += (size_t)N*HN;
  float* relw = w; w += 16;
  int* ip   = (int*)w;
  int* cnt0 = ip; ip += N;
  int* cnt1 = ip; ip += N;
  int* rp0  = ip; ip += N+1;
  int* rp1  = ip; ip += N+1;
  int* cur0 = ip; ip += N;
  int* cur1 = ip; ip += N;
  int* part0= ip; ip += 256;
  int* part1= ip; ip += 256;
  int* csr0 = ip; ip += E;
  int* csr1 = ip; ip += E;

  const int nwb = (N + 3) / 4;
  dim3 ggrid((N + 63)/64, 4);

  // 4 GEMMs: hd (shared by both relations + z_dst), hs0, hs1, nb
  gemm_bias_256<<<ggrid, 256, 0, stream>>>(hA, node_W,         node_b,     outA, N);
  gemm_bias_256<<<ggrid, 256, 0, stream>>>(hB, edge_W,         edge_b,     hs0,  N);
  gemm_bias_256<<<ggrid, 256, 0, stream>>>(hB, edge_W + D*D,   edge_b + D, hs1,  N);
  gemm_bias_256<<<ggrid, 256, 0, stream>>>(hB, node_W + D*D,   node_b + D, outB, N);

  attn_vec_kernel<<<nwb, 256, 0, stream>>>(hs0, hs1, outA, srcA_W, srcA_b, dstA_W, dstA_b,
                                           as0, as1, ad0, ad1, N);
  rel_kernel<<<1, 64, 0, stream>>>(rel_emb, relA_W, relA_b, relw);

  // CSR build for both relations
  zero_int<<<(2*N + 255)/256, 256, 0, stream>>>(cnt0, 2*N);
  hist_kernel<<<(E + 255)/256, 256, 0, stream>>>(dst0, dst1, cnt0, cnt1, E);
  const int nchunk = (N + 1023)/1024;
  scan1<<<nchunk, 1024, 0, stream>>>(cnt0, rp0, part0, N);
  scan1<<<nchunk, 1024, 0, stream>>>(cnt1, rp1, part1, N);
  scan2<<<1, 64, 0, stream>>>(part0, nchunk, rp0 + N);
  scan2<<<1, 64, 0, stream>>>(part1, nchunk, rp1 + N);
  scan3<<<nchunk, 1024, 0, stream>>>(rp0, cur0, part0, N);
  scan3<<<nchunk, 1024, 0, stream>>>(rp1, cur1, part1, N);
  scatter_kernel<<<(E + 255)/256, 256, 0, stream>>>(src0, dst0, cur0, csr0,
                                                    src1, dst1, cur1, csr1, E);

  // edge softmax + aggregation (both relations via grid.y)
  dim3 agrid(nwb, 2);
  aggregate_kernel<<<agrid, 256, 0, stream>>>(rp0, csr0, as0, ad0, hs0, z0,
                                              rp1, csr1, as1, ad1, hs1, z1, N);

  // epilogues
  fusionA_kernel<<<nwb, 256, 0, stream>>>(z0, z1, outA, hA, semS_W, semS_b, semD_W, semD_b,
                                          relw, N);
  fusionB_kernel<<<nwb, 256, 0, stream>>>(outB, hB, N);
}

// Round 8
// 702.156 us; speedup vs baseline: 1.3423x; 1.3423x over previous
//
#include <hip/hip_runtime.h>
#include <math.h>

#define D 256
#define HN 4
#define HT 4

typedef __bf16 bf16x8 __attribute__((ext_vector_type(8)));
typedef float  f32x16 __attribute__((ext_vector_type(16)));

__device__ __forceinline__ float lrelu(float x){ return x > 0.f ? x : 0.01f*x; }
__device__ __forceinline__ float gelu_exact(float x){ return 0.5f*x*(1.f+erff(x*0.70710678118654752f)); }

__device__ __forceinline__ float wred_sum(float v){
#pragma unroll
  for (int o = 32; o > 0; o >>= 1) v += __shfl_xor(v, o);
  return v;
}
__device__ __forceinline__ float4 wred_sum4(float4 v){
  v.x = wred_sum(v.x); v.y = wred_sum(v.y); v.z = wred_sum(v.z); v.w = wred_sum(v.w);
  return v;
}

#define ACC4(p, s, w) do { (p).x = fmaf((s),(w).x,(p).x); (p).y = fmaf((s),(w).y,(p).y); \
                           (p).z = fmaf((s),(w).z,(p).z); (p).w = fmaf((s),(w).w,(p).w); } while(0)

// ---------------------------------------------------------------------------
// Weight prep: Wt[mat][n][k] = W[mat][k][n] split into bf16 hi/lo.
// mats: 0=node_W[0], 1=node_W[1], 2=edge_W[0], 3=edge_W[1]
// ---------------------------------------------------------------------------
__global__ void wt_setup(const float* __restrict__ nodeW, const float* __restrict__ edgeW,
                         __bf16* __restrict__ WtHi, __bf16* __restrict__ WtLo)
{
  int idx = blockIdx.x*256 + threadIdx.x;       // 4*65536 total
  int mat = idx >> 16;
  int e   = idx & 65535;
  int n   = e & 255;        // fast-varying -> coalesced read
  int k   = e >> 8;
  const float* src = (mat==0)? nodeW : (mat==1)? nodeW+65536 : (mat==2)? edgeW : edgeW+65536;
  float x = src[k*256 + n];
  __bf16 hi = (__bf16)x;
  __bf16 lo = (__bf16)(x - (float)hi);
  size_t o = (size_t)mat*65536 + (size_t)n*256 + k;
  WtHi[o] = hi;
  WtLo[o] = lo;
}

// ---------------------------------------------------------------------------
// C[M x 256] = A[M x 256] @ W + bias via split-bf16 MFMA (3 terms).
// BM=128, BN=128, BK=32, 256 threads (4 waves, 2x2 of 64x64 wave tiles).
// LDS slot-major layout: region[slot s(4)][row(128)][8 k] bf16, slot stride
// padded to 2064B -> conflict-free b128 reads and writes.
// Regions: AH@0, AL@8256, WH@16512, WL@24768  (total 33024 B)
// ---------------------------------------------------------------------------
__device__ __forceinline__ void cvt8(const float4 a, const float4 b, bf16x8& h, bf16x8& l){
  float v0=a.x,v1=a.y,v2=a.z,v3=a.w,v4=b.x,v5=b.y,v6=b.z,v7=b.w;
  __bf16 t;
  t=(__bf16)v0; h[0]=t; l[0]=(__bf16)(v0-(float)t);
  t=(__bf16)v1; h[1]=t; l[1]=(__bf16)(v1-(float)t);
  t=(__bf16)v2; h[2]=t; l[2]=(__bf16)(v2-(float)t);
  t=(__bf16)v3; h[3]=t; l[3]=(__bf16)(v3-(float)t);
  t=(__bf16)v4; h[4]=t; l[4]=(__bf16)(v4-(float)t);
  t=(__bf16)v5; h[5]=t; l[5]=(__bf16)(v5-(float)t);
  t=(__bf16)v6; h[6]=t; l[6]=(__bf16)(v6-(float)t);
  t=(__bf16)v7; h[7]=t; l[7]=(__bf16)(v7-(float)t);
}

__global__ __launch_bounds__(256) void gemm_mfma(
    const float* __restrict__ A, const __bf16* __restrict__ WtHi, const __bf16* __restrict__ WtLo,
    const float* __restrict__ bias, float* __restrict__ C, int M)
{
  __shared__ __align__(16) char smem[33024];
  const int tid  = threadIdx.x;
  const int bm   = blockIdx.x * 128;
  const int bn   = blockIdx.y * 128;
  const int lane = tid & 63;
  const int wid  = tid >> 6;
  const int wm   = wid >> 1, wn = wid & 1;

  f32x16 acc[2][2] = {};

  // staging mapping: thread -> (row, k-quarter)
  const int sm_row = tid >> 1;            // 0..127
  const int sk     = (tid & 1) * 16;      // k offset 0 or 16 within BK
  int arow = bm + sm_row; if (arow >= M) arow = M - 1;
  const float*  gA  = A    + (size_t)arow*256 + sk;
  const __bf16* gWh = WtHi + (size_t)(bn + sm_row)*256 + sk;
  const __bf16* gWl = WtLo + (size_t)(bn + sm_row)*256 + sk;
  const int s0  = (tid & 1) * 2;          // first slot this thread writes
  const int wrO = sm_row * 16;            // byte offset within a slot

  float4 f0,f1,f2,f3; uint4 u0,u1,u2,u3;
  f0 = *(const float4*)(gA + 0);  f1 = *(const float4*)(gA + 4);
  f2 = *(const float4*)(gA + 8);  f3 = *(const float4*)(gA + 12);
  u0 = *(const uint4*)(gWh + 0);  u1 = *(const uint4*)(gWh + 8);
  u2 = *(const uint4*)(gWl + 0);  u3 = *(const uint4*)(gWl + 8);

  for (int it = 0; it < 8; ++it) {
    bf16x8 h0,h1,l0,l1;
    cvt8(f0, f1, h0, l0);
    cvt8(f2, f3, h1, l1);
    __syncthreads();                       // previous iteration's readers done
    *(bf16x8*)(smem +         s0   *2064 + wrO) = h0;
    *(bf16x8*)(smem +        (s0+1)*2064 + wrO) = h1;
    *(bf16x8*)(smem +  8256 + s0   *2064 + wrO) = l0;
    *(bf16x8*)(smem +  8256 +(s0+1)*2064 + wrO) = l1;
    *(uint4*)(smem + 16512 + s0   *2064 + wrO) = u0;
    *(uint4*)(smem + 16512 +(s0+1)*2064 + wrO) = u1;
    *(uint4*)(smem + 24768 + s0   *2064 + wrO) = u2;
    *(uint4*)(smem + 24768 +(s0+1)*2064 + wrO) = u3;
    if (it < 7) {                          // prefetch next K-tile while computing
      int k0 = (it+1)*32;
      f0 = *(const float4*)(gA + k0 + 0);  f1 = *(const float4*)(gA + k0 + 4);
      f2 = *(const float4*)(gA + k0 + 8);  f3 = *(const float4*)(gA + k0 + 12);
      u0 = *(const uint4*)(gWh + k0);      u1 = *(const uint4*)(gWh + k0 + 8);
      u2 = *(const uint4*)(gWl + k0);      u3 = *(const uint4*)(gWl + k0 + 8);
    }
    __syncthreads();
#pragma unroll
    for (int ks = 0; ks < 2; ++ks) {
      const int fo = (ks*2 + (lane>>5))*2064 + (lane&31)*16;
      bf16x8 aH0 = *(const bf16x8*)(smem +         fo + (wm*64    )*16);
      bf16x8 aH1 = *(const bf16x8*)(smem +         fo + (wm*64+32 )*16);
      bf16x8 aL0 = *(const bf16x8*)(smem +  8256 + fo + (wm*64    )*16);
      bf16x8 aL1 = *(const bf16x8*)(smem +  8256 + fo + (wm*64+32 )*16);
      bf16x8 bH0 = *(const bf16x8*)(smem + 16512 + fo + (wn*64    )*16);
      bf16x8 bH1 = *(const bf16x8*)(smem + 16512 + fo + (wn*64+32 )*16);
      bf16x8 bL0 = *(const bf16x8*)(smem + 24768 + fo + (wn*64    )*16);
      bf16x8 bL1 = *(const bf16x8*)(smem + 24768 + fo + (wn*64+32 )*16);
      acc[0][0] = __builtin_amdgcn_mfma_f32_32x32x16_bf16(aH0,bH0,acc[0][0],0,0,0);
      acc[0][0] = __builtin_amdgcn_mfma_f32_32x32x16_bf16(aH0,bL0,acc[0][0],0,0,0);
      acc[0][0] = __builtin_amdgcn_mfma_f32_32x32x16_bf16(aL0,bH0,acc[0][0],0,0,0);
      acc[0][1] = __builtin_amdgcn_mfma_f32_32x32x16_bf16(aH0,bH1,acc[0][1],0,0,0);
      acc[0][1] = __builtin_amdgcn_mfma_f32_32x32x16_bf16(aH0,bL1,acc[0][1],0,0,0);
      acc[0][1] = __builtin_amdgcn_mfma_f32_32x32x16_bf16(aL0,bH1,acc[0][1],0,0,0);
      acc[1][0] = __builtin_amdgcn_mfma_f32_32x32x16_bf16(aH1,bH0,acc[1][0],0,0,0);
      acc[1][0] = __builtin_amdgcn_mfma_f32_32x32x16_bf16(aH1,bL0,acc[1][0],0,0,0);
      acc[1][0] = __builtin_amdgcn_mfma_f32_32x32x16_bf16(aL1,bH0,acc[1][0],0,0,0);
      acc[1][1] = __builtin_amdgcn_mfma_f32_32x32x16_bf16(aH1,bH1,acc[1][1],0,0,0);
      acc[1][1] = __builtin_amdgcn_mfma_f32_32x32x16_bf16(aH1,bL1,acc[1][1],0,0,0);
      acc[1][1] = __builtin_amdgcn_mfma_f32_32x32x16_bf16(aL1,bH1,acc[1][1],0,0,0);
    }
  }

  // epilogue: +bias, scalar stores (coalesced per reg across lanes 0..31)
  const int col = bn + wn*64 + (lane&31);
#pragma unroll
  for (int fn = 0; fn < 2; ++fn) {
    float bval = bias[col + fn*32];
#pragma unroll
    for (int fm = 0; fm < 2; ++fm) {
      int rbase = bm + wm*64 + fm*32 + 4*(lane>>5);
#pragma unroll
      for (int r = 0; r < 16; ++r) {
        int row = rbase + (r&3) + 8*(r>>2);
        if (row < M) C[(size_t)row*256 + col + fn*32] = acc[fm][fn][r] + bval;
      }
    }
  }
}

// ---------------------------------------------------------------------------
// Per-node attention projections.
// ---------------------------------------------------------------------------
__global__ __launch_bounds__(256) void attn_vec_kernel(
    const float* __restrict__ hs0, const float* __restrict__ hs1,
    const float* __restrict__ hd,
    const float* __restrict__ srcA_W, const float* __restrict__ srcA_b,
    const float* __restrict__ dstA_W, const float* __restrict__ dstA_b,
    float* __restrict__ as0, float* __restrict__ as1,
    float* __restrict__ ad0, float* __restrict__ ad1, int N)
{
  int n = blockIdx.x*4 + (threadIdx.x >> 6);
  if (n >= N) return;
  int lane = threadIdx.x & 63;
  int d0 = lane << 2;
  const float4* Ws = (const float4*)srcA_W;
  const float4* Wd = (const float4*)dstA_W;
  float4 r0 = ((const float4*)hs0)[(size_t)n*64 + lane];
  float4 r1 = ((const float4*)hs1)[(size_t)n*64 + lane];
  float4 rd = ((const float4*)hd )[(size_t)n*64 + lane];
  float4 p0 = make_float4(0,0,0,0), p1 = make_float4(0,0,0,0);
  float4 q0 = make_float4(0,0,0,0), q1 = make_float4(0,0,0,0);
  float4 w;
  w = Ws[d0+0]; ACC4(p0, r0.x, w);
  w = Ws[d0+1]; ACC4(p0, r0.y, w);
  w = Ws[d0+2]; ACC4(p0, r0.z, w);
  w = Ws[d0+3]; ACC4(p0, r0.w, w);
  w = Ws[256+d0+0]; ACC4(p1, r1.x, w);
  w = Ws[256+d0+1]; ACC4(p1, r1.y, w);
  w = Ws[256+d0+2]; ACC4(p1, r1.z, w);
  w = Ws[256+d0+3]; ACC4(p1, r1.w, w);
  w = Wd[d0+0]; ACC4(q0, rd.x, w);
  w = Wd[d0+1]; ACC4(q0, rd.y, w);
  w = Wd[d0+2]; ACC4(q0, rd.z, w);
  w = Wd[d0+3]; ACC4(q0, rd.w, w);
  w = Wd[256+d0+0]; ACC4(q1, rd.x, w);
  w = Wd[256+d0+1]; ACC4(q1, rd.y, w);
  w = Wd[256+d0+2]; ACC4(q1, rd.z, w);
  w = Wd[256+d0+3]; ACC4(q1, rd.w, w);
  p0 = wred_sum4(p0); p1 = wred_sum4(p1); q0 = wred_sum4(q0); q1 = wred_sum4(q1);
  if (lane == 0) {
    float4 b;
    b = *(const float4*)(srcA_b + 0);
    ((float4*)as0)[n] = make_float4(p0.x+b.x, p0.y+b.y, p0.z+b.z, p0.w+b.w);
    b = *(const float4*)(srcA_b + 4);
    ((float4*)as1)[n] = make_float4(p1.x+b.x, p1.y+b.y, p1.z+b.z, p1.w+b.w);
    b = *(const float4*)(dstA_b + 0);
    ((float4*)ad0)[n] = make_float4(q0.x+b.x, q0.y+b.y, q0.z+b.z, q0.w+b.w);
    b = *(const float4*)(dstA_b + 4);
    ((float4*)ad1)[n] = make_float4(q1.x+b.x, q1.y+b.y, q1.z+b.z, q1.w+b.w);
  }
}

// rel attention (node-invariant), pre-scaled by (1-ALPHA)=0.5
__global__ void rel_kernel(const float* __restrict__ rel_emb, const float* __restrict__ relA_W,
                           const float* __restrict__ relA_b, float* __restrict__ rel_out)
{
  int t = threadIdx.x;
  if (t < 8) {
    int r = t >> 2, h = t & 3;
    float s = relA_b[r*4+h];
    for (int d = 0; d < 256; ++d)
      s = fmaf(rel_emb[r*256+d], relA_W[(size_t)(r*256+d)*4+h], s);
    s = lrelu(s);
    float other = __shfl_xor(s, 4);
    float mm = fmaxf(s, other);
    float e  = expf(s - mm), eo = expf(other - mm);
    rel_out[r*4+h] = 0.5f * e / (e + eo);
  }
}

// ---------------------------------------------------------------------------
// CSR build helpers
// ---------------------------------------------------------------------------
__global__ void zero_int(int* p, int n){
  int i = blockIdx.x*blockDim.x + threadIdx.x;
  if (i < n) p[i] = 0;
}

__global__ void hist_kernel(const int* __restrict__ dst0, const int* __restrict__ dst1,
                            int* c0, int* c1, int E){
  int e = blockIdx.x*256 + threadIdx.x;
  if (e < E) { atomicAdd(&c0[dst0[e]], 1); atomicAdd(&c1[dst1[e]], 1); }
}

__global__ __launch_bounds__(1024) void scan1(const int* __restrict__ cnt0, const int* __restrict__ cnt1,
                                              int* __restrict__ rp0, int* __restrict__ rp1,
                                              int* __restrict__ part0, int* __restrict__ part1, int n){
  const int* cnt = blockIdx.y ? cnt1 : cnt0;
  int* excl = blockIdx.y ? rp1 : rp0;
  int* part = blockIdx.y ? part1 : part0;
  __shared__ int sm[1024];
  int tid = threadIdx.x;
  int gid = blockIdx.x*1024 + tid;
  int v = (gid < n) ? cnt[gid] : 0;
  sm[tid] = v; __syncthreads();
  for (int off = 1; off < 1024; off <<= 1){
    int t = sm[tid];
    if (tid >= off) t += sm[tid-off];
    __syncthreads();
    sm[tid] = t; __syncthreads();
  }
  if (gid < n) excl[gid] = sm[tid] - v;
  if (tid == 1023) part[blockIdx.x] = sm[1023];
}

__global__ void scan2(int* part0, int* part1, int nchunk, int* tot0, int* tot1){
  if (threadIdx.x == 0 && blockIdx.x == 0){
    int run = 0;
    for (int i = 0; i < nchunk; ++i){ int t = part0[i]; part0[i] = run; run += t; }
    *tot0 = run;
    run = 0;
    for (int i = 0; i < nchunk; ++i){ int t = part1[i]; part1[i] = run; run += t; }
    *tot1 = run;
  }
}

__global__ __launch_bounds__(1024) void scan3(int* __restrict__ rp0, int* __restrict__ rp1,
                                              int* __restrict__ cur0, int* __restrict__ cur1,
                                              const int* __restrict__ part0, const int* __restrict__ part1, int n){
  int* rp  = blockIdx.y ? rp1 : rp0;
  int* cur = blockIdx.y ? cur1 : cur0;
  const int* part = blockIdx.y ? part1 : part0;
  int gid = blockIdx.x*1024 + threadIdx.x;
  if (gid < n){ int v = rp[gid] + part[blockIdx.x]; rp[gid] = v; cur[gid] = v; }
}

__global__ void scatter_kernel(const int* __restrict__ src0, const int* __restrict__ dst0,
                               int* cur0, int* __restrict__ csr0,
                               const int* __restrict__ src1, const int* __restrict__ dst1,
                               int* cur1, int* __restrict__ csr1, int E){
  int e = blockIdx.x*256 + threadIdx.x;
  if (e < E){
    int p = atomicAdd(&cur0[dst0[e]], 1); csr0[p] = src0[e];
    p = atomicAdd(&cur1[dst1[e]], 1); csr1[p] = src1[e];
  }
}

// ---------------------------------------------------------------------------
// Fused per-dst aggregation (both relations) + semantic/relation attention
// fusion + gelu + normalize. One wave per dst node.
// Softmax shift-invariance: logits bounded (|a|<~6) -> skip segment-max pass.
// exb holds unnormalized exp per edge (CSR order); vmcnt(0) fence + volatile
// readback gives same-wave cross-lane visibility (vmcnt is wave-wide; L1 is
// write-through; volatile loads are sc0/L1-bypass; CSR segments disjoint).
// ---------------------------------------------------------------------------
__device__ __forceinline__ float4 agg_one(
    const int* __restrict__ rp, const int* __restrict__ csr,
    const float* __restrict__ as, const float* __restrict__ ad,
    const float* __restrict__ hs, float* __restrict__ exb,
    int n, int lane, int h)
{
  int start = rp[n];
  int cnt   = rp[n+1] - start;
  float4 acc = make_float4(0,0,0,0);
  if (cnt == 0) return acc;
  float4 adv = *(const float4*)(ad + (size_t)n*4);
  float4 ssum = make_float4(0,0,0,0);
  for (int i = lane; i < cnt; i += 64) {
    int s = csr[start+i];
    float4 a = *(const float4*)(as + (size_t)s*4);
    float4 e;
    e.x = __expf(lrelu(a.x+adv.x));
    e.y = __expf(lrelu(a.y+adv.y));
    e.z = __expf(lrelu(a.z+adv.z));
    e.w = __expf(lrelu(a.w+adv.w));
    *(float4*)(exb + (size_t)(start+i)*4) = e;
    ssum.x += e.x; ssum.y += e.y; ssum.z += e.z; ssum.w += e.w;
  }
  ssum = wred_sum4(ssum);
  asm volatile("s_waitcnt vmcnt(0)" ::: "memory");   // stores visible
  float sh  = h==0?ssum.x : h==1?ssum.y : h==2?ssum.z : ssum.w;
  float invh = 1.f / sh;
  const volatile float* exv = exb;
  const float4* hsv = (const float4*)hs;
  int i = 0;
  for (; i+2 <= cnt; i += 2) {
    int sa = csr[start+i], sb = csr[start+i+1];
    float wa = exv[(size_t)(start+i)*4 + h];
    float wb = exv[(size_t)(start+i+1)*4 + h];
    float4 va = hsv[(size_t)sa*64 + lane];
    float4 vb = hsv[(size_t)sb*64 + lane];
    acc.x = fmaf(va.x,wa,acc.x); acc.y = fmaf(va.y,wa,acc.y);
    acc.z = fmaf(va.z,wa,acc.z); acc.w = fmaf(va.w,wa,acc.w);
    acc.x = fmaf(vb.x,wb,acc.x); acc.y = fmaf(vb.y,wb,acc.y);
    acc.z = fmaf(vb.z,wb,acc.z); acc.w = fmaf(vb.w,wb,acc.w);
  }
  if (i < cnt) {
    int sa = csr[start+i];
    float wa = exv[(size_t)(start+i)*4 + h];
    float4 va = hsv[(size_t)sa*64 + lane];
    acc.x = fmaf(va.x,wa,acc.x); acc.y = fmaf(va.y,wa,acc.y);
    acc.z = fmaf(va.z,wa,acc.z); acc.w = fmaf(va.w,wa,acc.w);
  }
  acc.x *= invh; acc.y *= invh; acc.z *= invh; acc.w *= invh;
  return acc;
}

__device__ __forceinline__ void sm2(float s0, float s1, float r0, float r1, float& o0, float& o1){
  float mm = fmaxf(s0, s1);
  float e0 = expf(s0-mm), e1 = expf(s1-mm);
  float inv = 1.f/(e0+e1);
  o0 = fmaf(0.5f*e0, inv, r0);
  o1 = fmaf(0.5f*e1, inv, r1);
}

__global__ __launch_bounds__(256) void aggregate_fused(
    const int* __restrict__ rp0, const int* __restrict__ csr0,
    const float* __restrict__ as0, const float* __restrict__ ad0,
    const float* __restrict__ hs0, float* __restrict__ exb0,
    const int* __restrict__ rp1, const int* __restrict__ csr1,
    const float* __restrict__ as1, const float* __restrict__ ad1,
    const float* __restrict__ hs1, float* __restrict__ exb1,
    float* __restrict__ hd_io, const float* __restrict__ hA,
    const float* __restrict__ semS_W, const float* __restrict__ semS_b,
    const float* __restrict__ semD_W, const float* __restrict__ semD_b,
    const float* __restrict__ relw, int N)
{
  int n = blockIdx.x*4 + (threadIdx.x >> 6);
  if (n >= N) return;
  int lane = threadIdx.x & 63;
  int h = lane >> 4;

  float4 a0 = agg_one(rp0, csr0, as0, ad0, hs0, exb0, n, lane, h);
  float4 a1 = agg_one(rp1, csr1, as1, ad1, hs1, exb1, n, lane, h);

  int d0 = lane << 2;
  float4 ad = ((float4*)hd_io)[(size_t)n*64 + lane];   // z_dst row
  float4 ha = ((const float4*)hA)[(size_t)n*64 + lane];
  float nz0 = wred_sum(a0.x*a0.x + a0.y*a0.y + a0.z*a0.z + a0.w*a0.w);
  float nz1 = wred_sum(a1.x*a1.x + a1.y*a1.y + a1.z*a1.z + a1.w*a1.w);
  float nzd = wred_sum(ad.x*ad.x + ad.y*ad.y + ad.z*ad.z + ad.w*ad.w);
  float i0  = 1.f / fmaxf(sqrtf(nz0), 1e-9f);
  float i1  = 1.f / fmaxf(sqrtf(nz1), 1e-9f);
  float idn = 1.f / fmaxf(sqrtf(nzd), 1e-9f);
  const float4* WS = (const float4*)semS_W;
  const float4* WD = (const float4*)semD_W;
  float4 p0 = make_float4(0,0,0,0), p1 = make_float4(0,0,0,0);
  float4 q0 = make_float4(0,0,0,0), q1 = make_float4(0,0,0,0);
  float4 w;
  w = WS[d0+0]; ACC4(p0, a0.x, w);
  w = WS[d0+1]; ACC4(p0, a0.y, w);
  w = WS[d0+2]; ACC4(p0, a0.z, w);
  w = WS[d0+3]; ACC4(p0, a0.w, w);
  w = WS[256+d0+0]; ACC4(p1, a1.x, w);
  w = WS[256+d0+1]; ACC4(p1, a1.y, w);
  w = WS[256+d0+2]; ACC4(p1, a1.z, w);
  w = WS[256+d0+3]; ACC4(p1, a1.w, w);
  w = WD[d0+0]; ACC4(q0, ad.x, w);
  w = WD[d0+1]; ACC4(q0, ad.y, w);
  w = WD[d0+2]; ACC4(q0, ad.z, w);
  w = WD[d0+3]; ACC4(q0, ad.w, w);
  w = WD[256+d0+0]; ACC4(q1, ad.x, w);
  w = WD[256+d0+1]; ACC4(q1, ad.y, w);
  w = WD[256+d0+2]; ACC4(q1, ad.z, w);
  w = WD[256+d0+3]; ACC4(q1, ad.w, w);
  p0 = wred_sum4(p0); p1 = wred_sum4(p1); q0 = wred_sum4(q0); q1 = wred_sum4(q1);
  float4 sb0 = *(const float4*)(semS_b + 0);
  float4 sb1 = *(const float4*)(semS_b + 4);
  float4 db0 = *(const float4*)(semD_b + 0);
  float4 db1 = *(const float4*)(semD_b + 4);
  float4 s0, s1;
  s0.x = lrelu(p0.x*i0 + sb0.x + q0.x*idn + db0.x);
  s0.y = lrelu(p0.y*i0 + sb0.y + q0.y*idn + db0.y);
  s0.z = lrelu(p0.z*i0 + sb0.z + q0.z*idn + db0.z);
  s0.w = lrelu(p0.w*i0 + sb0.w + q0.w*idn + db0.w);
  s1.x = lrelu(p1.x*i1 + sb1.x + q1.x*idn + db1.x);
  s1.y = lrelu(p1.y*i1 + sb1.y + q1.y*idn + db1.y);
  s1.z = lrelu(p1.z*i1 + sb1.z + q1.z*idn + db1.z);
  s1.w = lrelu(p1.w*i1 + sb1.w + q1.w*idn + db1.w);
  float4 at0, at1;
  sm2(s0.x, s1.x, relw[0], relw[4], at0.x, at1.x);
  sm2(s0.y, s1.y, relw[1], relw[5], at0.y, at1.y);
  sm2(s0.z, s1.z, relw[2], relw[6], at0.z, at1.z);
  sm2(s0.w, s1.w, relw[3], relw[7], at0.w, at1.w);
  float w0 = h==0 ? at0.x : h==1 ? at0.y : h==2 ? at0.z : at0.w;
  float w1 = h==0 ? at1.x : h==1 ? at1.y : h==2 ? at1.z : at1.w;
  float4 x;
  x.x = fmaf(a0.x, w0, fmaf(a1.x, w1, ha.x));
  x.y = fmaf(a0.y, w0, fmaf(a1.y, w1, ha.y));
  x.z = fmaf(a0.z, w0, fmaf(a1.z, w1, ha.z));
  x.w = fmaf(a0.w, w0, fmaf(a1.w, w1, ha.w));
  float4 g;
  g.x = gelu_exact(x.x); g.y = gelu_exact(x.y); g.z = gelu_exact(x.z); g.w = gelu_exact(x.w);
  float ng = wred_sum(g.x*g.x + g.y*g.y + g.z*g.z + g.w*g.w);
  float inv = 1.f / fmaxf(sqrtf(ng), 1e-9f);
  g.x *= inv; g.y *= inv; g.z *= inv; g.w *= inv;
  ((float4*)hd_io)[(size_t)n*64 + lane] = g;
}

// Node type B fallback: out_B = normalize(gelu(nb + h_B)); nb lives in outB region.
__global__ __launch_bounds__(256) void fusionB_kernel(float* __restrict__ outB,
                                                      const float* __restrict__ hB, int N)
{
  int n = blockIdx.x*4 + (threadIdx.x >> 6);
  if (n >= N) return;
  int lane = threadIdx.x & 63;
  float4 x = ((float4*)outB)[(size_t)n*64 + lane];
  float4 b = ((const float4*)hB)[(size_t)n*64 + lane];
  x.x += b.x; x.y += b.y; x.z += b.z; x.w += b.w;
  float4 g;
  g.x = gelu_exact(x.x); g.y = gelu_exact(x.y); g.z = gelu_exact(x.z); g.w = gelu_exact(x.w);
  float ng = wred_sum(g.x*g.x + g.y*g.y + g.z*g.z + g.w*g.w);
  float inv = 1.f / fmaxf(sqrtf(ng), 1e-9f);
  g.x *= inv; g.y *= inv; g.z *= inv; g.w *= inv;
  ((float4*)outB)[(size_t)n*64 + lane] = g;
}

// ---------------------------------------------------------------------------
extern "C" void kernel_launch(void* const* d_in, const int* in_sizes, int n_in,
                              void* d_out, int out_size, void* d_ws, size_t ws_size,
                              hipStream_t stream)
{
  const float* hA     = (const float*)d_in[0];
  const float* hB     = (const float*)d_in[1];
  const int*   src0   = (const int*)d_in[2];
  const int*   dst0   = (const int*)d_in[3];
  const int*   src1   = (const int*)d_in[4];
  const int*   dst1   = (const int*)d_in[5];
  const float* node_W = (const float*)d_in[6];
  const float* node_b = (const float*)d_in[7];
  const float* edge_W = (const float*)d_in[8];
  const float* edge_b = (const float*)d_in[9];
  const float* srcA_W = (const float*)d_in[10];
  const float* srcA_b = (const float*)d_in[11];
  const float* dstA_W = (const float*)d_in[12];
  const float* dstA_b = (const float*)d_in[13];
  const float* semS_W = (const float*)d_in[14];
  const float* semS_b = (const float*)d_in[15];
  const float* semD_W = (const float*)d_in[16];
  const float* semD_b = (const float*)d_in[17];
  const float* relA_W = (const float*)d_in[18];
  const float* relA_b = (const float*)d_in[19];
  const float* rel_emb= (const float*)d_in[20];

  const int N = in_sizes[0] / D;
  const int E = in_sizes[2];

  float* out  = (float*)d_out;
  float* outA = out;                    // scratch for hd (=z_dst), then final out_A
  float* outB = out + (size_t)N*D;      // scratch for nb, then final out_B

  float* w = (float*)d_ws;
  float* hs0  = w; w += (size_t)N*D;
  float* hs1  = w; w += (size_t)N*D;
  float* exb0 = w; w += (size_t)E*HN;
  float* exb1 = w; w += (size_t)E*HN;
  float* as0  = w; w += (size_t)N*HN;
  float* as1  = w; w += (size_t)N*HN;
  float* ad0  = w; w += (size_t)N*HN;
  float* ad1  = w; w += (size_t)N*HN;
  float* relw = w; w += 16;
  __bf16* WtHi = (__bf16*)w; w += 131072;   // 4 mats * 65536 bf16 = 512KB
  __bf16* WtLo = (__bf16*)w; w += 131072;
  int* ip   = (int*)w;
  int* cnt0 = ip; ip += N;
  int* cnt1 = ip; ip += N;
  int* rp0  = ip; ip += N+1;
  int* rp1  = ip; ip += N+1;
  int* cur0 = ip; ip += N;
  int* cur1 = ip; ip += N;
  int* part0= ip; ip += 256;
  int* part1= ip; ip += 256;
  int* csr0 = ip; ip += E;
  int* csr1 = ip; ip += E;

  const int nwb = (N + 3) / 4;
  dim3 ggrid((N + 127)/128, 2);

  // weight transpose + bf16 hi/lo split
  wt_setup<<<1024, 256, 0, stream>>>(node_W, edge_W, WtHi, WtLo);

  // 4 GEMMs on the matrix pipe: hd(z_dst), hs0, hs1, nb
  gemm_mfma<<<ggrid, 256, 0, stream>>>(hA, WtHi + 0*65536, WtLo + 0*65536, node_b,       outA, N);
  gemm_mfma<<<ggrid, 256, 0, stream>>>(hB, WtHi + 2*65536, WtLo + 2*65536, edge_b,       hs0,  N);
  gemm_mfma<<<ggrid, 256, 0, stream>>>(hB, WtHi + 3*65536, WtLo + 3*65536, edge_b + D,   hs1,  N);
  gemm_mfma<<<ggrid, 256, 0, stream>>>(hB, WtHi + 1*65536, WtLo + 1*65536, node_b + D,   outB, N);

  attn_vec_kernel<<<nwb, 256, 0, stream>>>(hs0, hs1, outA, srcA_W, srcA_b, dstA_W, dstA_b,
                                           as0, as1, ad0, ad1, N);
  rel_kernel<<<1, 64, 0, stream>>>(rel_emb, relA_W, relA_b, relw);

  // CSR build for both relations
  zero_int<<<(2*N + 255)/256, 256, 0, stream>>>(cnt0, 2*N);
  hist_kernel<<<(E + 255)/256, 256, 0, stream>>>(dst0, dst1, cnt0, cnt1, E);
  const int nchunk = (N + 1023)/1024;
  dim3 sgrid(nchunk, 2);
  scan1<<<sgrid, 1024, 0, stream>>>(cnt0, cnt1, rp0, rp1, part0, part1, N);
  scan2<<<1, 64, 0, stream>>>(part0, part1, nchunk, rp0 + N, rp1 + N);
  scan3<<<sgrid, 1024, 0, stream>>>(rp0, rp1, cur0, cur1, part0, part1, N);
  scatter_kernel<<<(E + 255)/256, 256, 0, stream>>>(src0, dst0, cur0, csr0,
                                                    src1, dst1, cur1, csr1, E);

  // fused edge-softmax + aggregation (both relations) + semantic fusion epilogue
  aggregate_fused<<<nwb, 256, 0, stream>>>(rp0, csr0, as0, ad0, hs0, exb0,
                                           rp1, csr1, as1, ad1, hs1, exb1,
                                           outA, hA, semS_W, semS_b, semD_W, semD_b,
                                           relw, N);

  fusionB_kernel<<<nwb, 256, 0, stream>>>(outB, hB, N);
}

// Round 10
// 629.554 us; speedup vs baseline: 1.4971x; 1.1153x over previous
//
#include <hip/hip_runtime.h>
#include <math.h>

#define D 256
#define HN 4
#define HT 4

typedef __bf16 bf16x8 __attribute__((ext_vector_type(8)));
typedef float  f32x16 __attribute__((ext_vector_type(16)));

__device__ __forceinline__ float lrelu(float x){ return x > 0.f ? x : 0.01f*x; }
__device__ __forceinline__ float gelu_exact(float x){ return 0.5f*x*(1.f+erff(x*0.70710678118654752f)); }

__device__ __forceinline__ float wred_sum(float v){
#pragma unroll
  for (int o = 32; o > 0; o >>= 1) v += __shfl_xor(v, o);
  return v;
}
__device__ __forceinline__ float4 wred_sum4(float4 v){
  v.x = wred_sum(v.x); v.y = wred_sum(v.y); v.z = wred_sum(v.z); v.w = wred_sum(v.w);
  return v;
}

#define ACC4(p, s, w) do { (p).x = fmaf((s),(w).x,(p).x); (p).y = fmaf((s),(w).y,(p).y); \
                           (p).z = fmaf((s),(w).z,(p).z); (p).w = fmaf((s),(w).w,(p).w); } while(0)

// ---------------------------------------------------------------------------
// Weight prep: Wt[mat][n][k] = W[mat][k][n] split into bf16 hi/lo.
// mats: 0=node_W[0], 1=node_W[1], 2=edge_W[0], 3=edge_W[1]
// ---------------------------------------------------------------------------
__global__ void wt_setup(const float* __restrict__ nodeW, const float* __restrict__ edgeW,
                         __bf16* __restrict__ WtHi, __bf16* __restrict__ WtLo)
{
  int idx = blockIdx.x*256 + threadIdx.x;       // 4*65536 total
  int mat = idx >> 16;
  int e   = idx & 65535;
  int n   = e & 255;        // fast-varying -> coalesced read
  int k   = e >> 8;
  const float* src = (mat==0)? nodeW : (mat==1)? nodeW+65536 : (mat==2)? edgeW : edgeW+65536;
  float x = src[k*256 + n];
  __bf16 hi = (__bf16)x;
  __bf16 lo = (__bf16)(x - (float)hi);
  size_t o = (size_t)mat*65536 + (size_t)n*256 + k;
  WtHi[o] = hi;
  WtLo[o] = lo;
}

// ---------------------------------------------------------------------------
// Batched: 4 GEMMs C[M x 256] = A @ W + bias via split-bf16 MFMA (3 terms).
// blockIdx.z selects (A, Wmat, bias, C). BM=128, BN=128, BK=32, 256 threads.
// LDS slot-major layout, slot stride 2064B -> conflict-free b128 r/w.
// ---------------------------------------------------------------------------
__device__ __forceinline__ void cvt8(const float4 a, const float4 b, bf16x8& h, bf16x8& l){
  float v0=a.x,v1=a.y,v2=a.z,v3=a.w,v4=b.x,v5=b.y,v6=b.z,v7=b.w;
  __bf16 t;
  t=(__bf16)v0; h[0]=t; l[0]=(__bf16)(v0-(float)t);
  t=(__bf16)v1; h[1]=t; l[1]=(__bf16)(v1-(float)t);
  t=(__bf16)v2; h[2]=t; l[2]=(__bf16)(v2-(float)t);
  t=(__bf16)v3; h[3]=t; l[3]=(__bf16)(v3-(float)t);
  t=(__bf16)v4; h[4]=t; l[4]=(__bf16)(v4-(float)t);
  t=(__bf16)v5; h[5]=t; l[5]=(__bf16)(v5-(float)t);
  t=(__bf16)v6; h[6]=t; l[6]=(__bf16)(v6-(float)t);
  t=(__bf16)v7; h[7]=t; l[7]=(__bf16)(v7-(float)t);
}

__global__ __launch_bounds__(256) void gemm_mfma4(
    const float* __restrict__ hA, const float* __restrict__ hB,
    const __bf16* __restrict__ WtHi, const __bf16* __restrict__ WtLo,
    const float* __restrict__ node_b, const float* __restrict__ edge_b,
    float* __restrict__ outA, float* __restrict__ hs0,
    float* __restrict__ hs1, float* __restrict__ outB, int M)
{
  const int z = blockIdx.z;
  const float* A    = (z==0)? hA : hB;
  const int    mat  = (z==0)? 0 : (z==1)? 2 : (z==2)? 3 : 1;
  const float* bias = (z==0)? node_b : (z==1)? edge_b : (z==2)? edge_b+256 : node_b+256;
  float*       C    = (z==0)? outA : (z==1)? hs0 : (z==2)? hs1 : outB;
  const __bf16* Wh  = WtHi + (size_t)mat*65536;
  const __bf16* Wl  = WtLo + (size_t)mat*65536;

  __shared__ __align__(16) char smem[33024];
  const int tid  = threadIdx.x;
  const int bm   = blockIdx.x * 128;
  const int bn   = blockIdx.y * 128;
  const int lane = tid & 63;
  const int wid  = tid >> 6;
  const int wm   = wid >> 1, wn = wid & 1;

  f32x16 acc[2][2] = {};

  const int sm_row = tid >> 1;            // 0..127
  const int sk     = (tid & 1) * 16;      // k offset 0 or 16 within BK
  int arow = bm + sm_row; if (arow >= M) arow = M - 1;
  const float*  gA  = A  + (size_t)arow*256 + sk;
  const __bf16* gWh = Wh + (size_t)(bn + sm_row)*256 + sk;
  const __bf16* gWl = Wl + (size_t)(bn + sm_row)*256 + sk;
  const int s0  = (tid & 1) * 2;          // first slot this thread writes
  const int wrO = sm_row * 16;            // byte offset within a slot

  float4 f0,f1,f2,f3; uint4 u0,u1,u2,u3;
  f0 = *(const float4*)(gA + 0);  f1 = *(const float4*)(gA + 4);
  f2 = *(const float4*)(gA + 8);  f3 = *(const float4*)(gA + 12);
  u0 = *(const uint4*)(gWh + 0);  u1 = *(const uint4*)(gWh + 8);
  u2 = *(const uint4*)(gWl + 0);  u3 = *(const uint4*)(gWl + 8);

  for (int it = 0; it < 8; ++it) {
    bf16x8 h0,h1,l0,l1;
    cvt8(f0, f1, h0, l0);
    cvt8(f2, f3, h1, l1);
    __syncthreads();                       // previous iteration's readers done
    *(bf16x8*)(smem +         s0   *2064 + wrO) = h0;
    *(bf16x8*)(smem +        (s0+1)*2064 + wrO) = h1;
    *(bf16x8*)(smem +  8256 + s0   *2064 + wrO) = l0;
    *(bf16x8*)(smem +  8256 +(s0+1)*2064 + wrO) = l1;
    *(uint4*)(smem + 16512 + s0   *2064 + wrO) = u0;
    *(uint4*)(smem + 16512 +(s0+1)*2064 + wrO) = u1;
    *(uint4*)(smem + 24768 + s0   *2064 + wrO) = u2;
    *(uint4*)(smem + 24768 +(s0+1)*2064 + wrO) = u3;
    if (it < 7) {                          // prefetch next K-tile while computing
      int k0 = (it+1)*32;
      f0 = *(const float4*)(gA + k0 + 0);  f1 = *(const float4*)(gA + k0 + 4);
      f2 = *(const float4*)(gA + k0 + 8);  f3 = *(const float4*)(gA + k0 + 12);
      u0 = *(const uint4*)(gWh + k0);      u1 = *(const uint4*)(gWh + k0 + 8);
      u2 = *(const uint4*)(gWl + k0);      u3 = *(const uint4*)(gWl + k0 + 8);
    }
    __syncthreads();
#pragma unroll
    for (int ks = 0; ks < 2; ++ks) {
      const int fo = (ks*2 + (lane>>5))*2064 + (lane&31)*16;
      bf16x8 aH0 = *(const bf16x8*)(smem +         fo + (wm*64    )*16);
      bf16x8 aH1 = *(const bf16x8*)(smem +         fo + (wm*64+32 )*16);
      bf16x8 aL0 = *(const bf16x8*)(smem +  8256 + fo + (wm*64    )*16);
      bf16x8 aL1 = *(const bf16x8*)(smem +  8256 + fo + (wm*64+32 )*16);
      bf16x8 bH0 = *(const bf16x8*)(smem + 16512 + fo + (wn*64    )*16);
      bf16x8 bH1 = *(const bf16x8*)(smem + 16512 + fo + (wn*64+32 )*16);
      bf16x8 bL0 = *(const bf16x8*)(smem + 24768 + fo + (wn*64    )*16);
      bf16x8 bL1 = *(const bf16x8*)(smem + 24768 + fo + (wn*64+32 )*16);
      acc[0][0] = __builtin_amdgcn_mfma_f32_32x32x16_bf16(aH0,bH0,acc[0][0],0,0,0);
      acc[0][0] = __builtin_amdgcn_mfma_f32_32x32x16_bf16(aH0,bL0,acc[0][0],0,0,0);
      acc[0][0] = __builtin_amdgcn_mfma_f32_32x32x16_bf16(aL0,bH0,acc[0][0],0,0,0);
      acc[0][1] = __builtin_amdgcn_mfma_f32_32x32x16_bf16(aH0,bH1,acc[0][1],0,0,0);
      acc[0][1] = __builtin_amdgcn_mfma_f32_32x32x16_bf16(aH0,bL1,acc[0][1],0,0,0);
      acc[0][1] = __builtin_amdgcn_mfma_f32_32x32x16_bf16(aL0,bH1,acc[0][1],0,0,0);
      acc[1][0] = __builtin_amdgcn_mfma_f32_32x32x16_bf16(aH1,bH0,acc[1][0],0,0,0);
      acc[1][0] = __builtin_amdgcn_mfma_f32_32x32x16_bf16(aH1,bL0,acc[1][0],0,0,0);
      acc[1][0] = __builtin_amdgcn_mfma_f32_32x32x16_bf16(aL1,bH0,acc[1][0],0,0,0);
      acc[1][1] = __builtin_amdgcn_mfma_f32_32x32x16_bf16(aH1,bH1,acc[1][1],0,0,0);
      acc[1][1] = __builtin_amdgcn_mfma_f32_32x32x16_bf16(aH1,bL1,acc[1][1],0,0,0);
      acc[1][1] = __builtin_amdgcn_mfma_f32_32x32x16_bf16(aL1,bH1,acc[1][1],0,0,0);
    }
  }

  // epilogue: +bias, scalar stores (coalesced per reg across lanes 0..31)
  const int col = bn + wn*64 + (lane&31);
#pragma unroll
  for (int fn = 0; fn < 2; ++fn) {
    float bval = bias[col + fn*32];
#pragma unroll
    for (int fm = 0; fm < 2; ++fm) {
      int rbase = bm + wm*64 + fm*32 + 4*(lane>>5);
#pragma unroll
      for (int r = 0; r < 16; ++r) {
        int row = rbase + (r&3) + 8*(r>>2);
        if (row < M) C[(size_t)row*256 + col + fn*32] = acc[fm][fn][r] + bval;
      }
    }
  }
}

// ---------------------------------------------------------------------------
// Per-node attention projections.
// ---------------------------------------------------------------------------
__global__ __launch_bounds__(256) void attn_vec_kernel(
    const float* __restrict__ hs0, const float* __restrict__ hs1,
    const float* __restrict__ hd,
    const float* __restrict__ srcA_W, const float* __restrict__ srcA_b,
    const float* __restrict__ dstA_W, const float* __restrict__ dstA_b,
    float* __restrict__ as0, float* __restrict__ as1,
    float* __restrict__ ad0, float* __restrict__ ad1, int N)
{
  int n = blockIdx.x*4 + (threadIdx.x >> 6);
  if (n >= N) return;
  int lane = threadIdx.x & 63;
  int d0 = lane << 2;
  const float4* Ws = (const float4*)srcA_W;
  const float4* Wd = (const float4*)dstA_W;
  float4 r0 = ((const float4*)hs0)[(size_t)n*64 + lane];
  float4 r1 = ((const float4*)hs1)[(size_t)n*64 + lane];
  float4 rd = ((const float4*)hd )[(size_t)n*64 + lane];
  float4 p0 = make_float4(0,0,0,0), p1 = make_float4(0,0,0,0);
  float4 q0 = make_float4(0,0,0,0), q1 = make_float4(0,0,0,0);
  float4 w;
  w = Ws[d0+0]; ACC4(p0, r0.x, w);
  w = Ws[d0+1]; ACC4(p0, r0.y, w);
  w = Ws[d0+2]; ACC4(p0, r0.z, w);
  w = Ws[d0+3]; ACC4(p0, r0.w, w);
  w = Ws[256+d0+0]; ACC4(p1, r1.x, w);
  w = Ws[256+d0+1]; ACC4(p1, r1.y, w);
  w = Ws[256+d0+2]; ACC4(p1, r1.z, w);
  w = Ws[256+d0+3]; ACC4(p1, r1.w, w);
  w = Wd[d0+0]; ACC4(q0, rd.x, w);
  w = Wd[d0+1]; ACC4(q0, rd.y, w);
  w = Wd[d0+2]; ACC4(q0, rd.z, w);
  w = Wd[d0+3]; ACC4(q0, rd.w, w);
  w = Wd[256+d0+0]; ACC4(q1, rd.x, w);
  w = Wd[256+d0+1]; ACC4(q1, rd.y, w);
  w = Wd[256+d0+2]; ACC4(q1, rd.z, w);
  w = Wd[256+d0+3]; ACC4(q1, rd.w, w);
  p0 = wred_sum4(p0); p1 = wred_sum4(p1); q0 = wred_sum4(q0); q1 = wred_sum4(q1);
  if (lane == 0) {
    float4 b;
    b = *(const float4*)(srcA_b + 0);
    ((float4*)as0)[n] = make_float4(p0.x+b.x, p0.y+b.y, p0.z+b.z, p0.w+b.w);
    b = *(const float4*)(srcA_b + 4);
    ((float4*)as1)[n] = make_float4(p1.x+b.x, p1.y+b.y, p1.z+b.z, p1.w+b.w);
    b = *(const float4*)(dstA_b + 0);
    ((float4*)ad0)[n] = make_float4(q0.x+b.x, q0.y+b.y, q0.z+b.z, q0.w+b.w);
    b = *(const float4*)(dstA_b + 4);
    ((float4*)ad1)[n] = make_float4(q1.x+b.x, q1.y+b.y, q1.z+b.z, q1.w+b.w);
  }
}

// rel attention (node-invariant), pre-scaled by (1-ALPHA)=0.5
__global__ void rel_kernel(const float* __restrict__ rel_emb, const float* __restrict__ relA_W,
                           const float* __restrict__ relA_b, float* __restrict__ rel_out)
{
  int t = threadIdx.x;
  if (t < 8) {
    int r = t >> 2, h = t & 3;
    float s = relA_b[r*4+h];
    for (int d = 0; d < 256; ++d)
      s = fmaf(rel_emb[r*256+d], relA_W[(size_t)(r*256+d)*4+h], s);
    s = lrelu(s);
    float other = __shfl_xor(s, 4);
    float mm = fmaxf(s, other);
    float e  = expf(s - mm), eo = expf(other - mm);
    rel_out[r*4+h] = 0.5f * e / (e + eo);
  }
}

// ---------------------------------------------------------------------------
// CSR build helpers
// ---------------------------------------------------------------------------
__global__ void zero_int(int* p, int n){
  int i = blockIdx.x*blockDim.x + threadIdx.x;
  if (i < n) p[i] = 0;
}

__global__ void hist_kernel(const int* __restrict__ dst0, const int* __restrict__ dst1,
                            int* c0, int* c1, int E){
  int e = blockIdx.x*256 + threadIdx.x;
  if (e < E) { atomicAdd(&c0[dst0[e]], 1); atomicAdd(&c1[dst1[e]], 1); }
}

__global__ __launch_bounds__(1024) void scan1(const int* __restrict__ cnt0, const int* __restrict__ cnt1,
                                              int* __restrict__ rp0, int* __restrict__ rp1,
                                              int* __restrict__ part0, int* __restrict__ part1, int n){
  const int* cnt = blockIdx.y ? cnt1 : cnt0;
  int* excl = blockIdx.y ? rp1 : rp0;
  int* part = blockIdx.y ? part1 : part0;
  __shared__ int sm[1024];
  int tid = threadIdx.x;
  int gid = blockIdx.x*1024 + tid;
  int v = (gid < n) ? cnt[gid] : 0;
  sm[tid] = v; __syncthreads();
  for (int off = 1; off < 1024; off <<= 1){
    int t = sm[tid];
    if (tid >= off) t += sm[tid-off];
    __syncthreads();
    sm[tid] = t; __syncthreads();
  }
  if (gid < n) excl[gid] = sm[tid] - v;
  if (tid == 1023) part[blockIdx.x] = sm[1023];
}

__global__ void scan2(int* part0, int* part1, int nchunk, int* tot0, int* tot1){
  if (threadIdx.x == 0 && blockIdx.x == 0){
    int run = 0;
    for (int i = 0; i < nchunk; ++i){ int t = part0[i]; part0[i] = run; run += t; }
    *tot0 = run;
    run = 0;
    for (int i = 0; i < nchunk; ++i){ int t = part1[i]; part1[i] = run; run += t; }
    *tot1 = run;
  }
}

__global__ __launch_bounds__(1024) void scan3(int* __restrict__ rp0, int* __restrict__ rp1,
                                              int* __restrict__ cur0, int* __restrict__ cur1,
                                              const int* __restrict__ part0, const int* __restrict__ part1, int n){
  int* rp  = blockIdx.y ? rp1 : rp0;
  int* cur = blockIdx.y ? cur1 : cur0;
  const int* part = blockIdx.y ? part1 : part0;
  int gid = blockIdx.x*1024 + threadIdx.x;
  if (gid < n){ int v = rp[gid] + part[blockIdx.x]; rp[gid] = v; cur[gid] = v; }
}

__global__ void scatter_kernel(const int* __restrict__ src0, const int* __restrict__ dst0,
                               int* cur0, int* __restrict__ csr0,
                               const int* __restrict__ src1, const int* __restrict__ dst1,
                               int* cur1, int* __restrict__ csr1, int E){
  int e = blockIdx.x*256 + threadIdx.x;
  if (e < E){
    int p = atomicAdd(&cur0[dst0[e]], 1); csr0[p] = src0[e];
    p = atomicAdd(&cur1[dst1[e]], 1); csr1[p] = src1[e];
  }
}

// ---------------------------------------------------------------------------
// Fused aggregation v2: one wave per (node, relation) — 2 nodes x 2 rels per
// 256-thread block. Single pass per edge: w=exp(lrelu(a)); acc+=w*hs; ssum+=w
// (each lane only needs its own head's denominator -> NO cross-lane reduce,
// no exp recompute pass, no global exb round-trip). rel1 wave passes its
// result through LDS; rel0 wave runs the fusion epilogue.
// Softmax shift-invariance: logits bounded -> skip segment-max (exact).
// ---------------------------------------------------------------------------
__device__ __forceinline__ void sm2(float s0, float s1, float r0, float r1, float& o0, float& o1){
  float mm = fmaxf(s0, s1);
  float e0 = expf(s0-mm), e1 = expf(s1-mm);
  float inv = 1.f/(e0+e1);
  o0 = fmaf(0.5f*e0, inv, r0);
  o1 = fmaf(0.5f*e1, inv, r1);
}

__global__ __launch_bounds__(256) void aggregate_fused2(
    const int* __restrict__ rp0, const int* __restrict__ csr0,
    const float* __restrict__ as0, const float* __restrict__ ad0,
    const float* __restrict__ hs0,
    const int* __restrict__ rp1, const int* __restrict__ csr1,
    const float* __restrict__ as1, const float* __restrict__ ad1,
    const float* __restrict__ hs1,
    float* __restrict__ hd_io, const float* __restrict__ hA,
    const float* __restrict__ semS_W, const float* __restrict__ semS_b,
    const float* __restrict__ semD_W, const float* __restrict__ semD_b,
    const float* __restrict__ relw, int N)
{
  __shared__ float4 a1_lds[2][64];
  const int tid    = threadIdx.x;
  const int lane   = tid & 63;
  const int wid    = tid >> 6;
  const int locn   = wid >> 1;       // 0/1: node within block
  const int rel    = wid & 1;        // 0/1: relation
  const int n      = blockIdx.x*2 + locn;
  const int h      = lane >> 4;
  const bool active = (n < N);

  float4 acc = make_float4(0.f,0.f,0.f,0.f);
  if (active) {
    const int*   rp  = rel ? rp1  : rp0;
    const int*   csr = rel ? csr1 : csr0;
    const float* as  = rel ? as1  : as0;
    const float* ad  = rel ? ad1  : ad0;
    const float* hs  = rel ? hs1  : hs0;
    int start = rp[n];
    int cnt   = rp[n+1] - start;
    if (cnt > 0) {
      float adh = ad[(size_t)n*4 + h];
      const float4* hsv = (const float4*)hs;
      float ssum = 0.f;
      int i = 0;
      for (; i+4 <= cnt; i += 4) {
        int s0 = csr[start+i], s1 = csr[start+i+1], s2 = csr[start+i+2], s3 = csr[start+i+3];
        float w0 = __expf(lrelu(as[(size_t)s0*4+h] + adh));
        float w1 = __expf(lrelu(as[(size_t)s1*4+h] + adh));
        float w2 = __expf(lrelu(as[(size_t)s2*4+h] + adh));
        float w3 = __expf(lrelu(as[(size_t)s3*4+h] + adh));
        float4 v0 = hsv[(size_t)s0*64 + lane];
        float4 v1 = hsv[(size_t)s1*64 + lane];
        float4 v2 = hsv[(size_t)s2*64 + lane];
        float4 v3 = hsv[(size_t)s3*64 + lane];
        acc.x = fmaf(v0.x,w0,acc.x); acc.y = fmaf(v0.y,w0,acc.y);
        acc.z = fmaf(v0.z,w0,acc.z); acc.w = fmaf(v0.w,w0,acc.w);
        acc.x = fmaf(v1.x,w1,acc.x); acc.y = fmaf(v1.y,w1,acc.y);
        acc.z = fmaf(v1.z,w1,acc.z); acc.w = fmaf(v1.w,w1,acc.w);
        acc.x = fmaf(v2.x,w2,acc.x); acc.y = fmaf(v2.y,w2,acc.y);
        acc.z = fmaf(v2.z,w2,acc.z); acc.w = fmaf(v2.w,w2,acc.w);
        acc.x = fmaf(v3.x,w3,acc.x); acc.y = fmaf(v3.y,w3,acc.y);
        acc.z = fmaf(v3.z,w3,acc.z); acc.w = fmaf(v3.w,w3,acc.w);
        ssum += w0 + w1 + w2 + w3;
      }
      for (; i < cnt; ++i) {
        int s = csr[start+i];
        float wv = __expf(lrelu(as[(size_t)s*4+h] + adh));
        float4 v = hsv[(size_t)s*64 + lane];
        acc.x = fmaf(v.x,wv,acc.x); acc.y = fmaf(v.y,wv,acc.y);
        acc.z = fmaf(v.z,wv,acc.z); acc.w = fmaf(v.w,wv,acc.w);
        ssum += wv;
      }
      float inv = 1.f / ssum;
      acc.x *= inv; acc.y *= inv; acc.z *= inv; acc.w *= inv;
    }
  }
  if (rel == 1) a1_lds[locn][lane] = acc;
  __syncthreads();
  if (rel == 1 || !active) return;

  // ---- fusion epilogue (rel0 wave of each node) ----
  float4 a0 = acc;
  float4 a1 = a1_lds[locn][lane];
  int d0 = lane << 2;
  float4 ad = ((float4*)hd_io)[(size_t)n*64 + lane];   // z_dst row
  float4 ha = ((const float4*)hA)[(size_t)n*64 + lane];
  float nz0 = wred_sum(a0.x*a0.x + a0.y*a0.y + a0.z*a0.z + a0.w*a0.w);
  float nz1 = wred_sum(a1.x*a1.x + a1.y*a1.y + a1.z*a1.z + a1.w*a1.w);
  float nzd = wred_sum(ad.x*ad.x + ad.y*ad.y + ad.z*ad.z + ad.w*ad.w);
  float i0  = 1.f / fmaxf(sqrtf(nz0), 1e-9f);
  float i1  = 1.f / fmaxf(sqrtf(nz1), 1e-9f);
  float idn = 1.f / fmaxf(sqrtf(nzd), 1e-9f);
  const float4* WS = (const float4*)semS_W;
  const float4* WD = (const float4*)semD_W;
  float4 p0 = make_float4(0,0,0,0), p1 = make_float4(0,0,0,0);
  float4 q0 = make_float4(0,0,0,0), q1 = make_float4(0,0,0,0);
  float4 w;
  w = WS[d0+0]; ACC4(p0, a0.x, w);
  w = WS[d0+1]; ACC4(p0, a0.y, w);
  w = WS[d0+2]; ACC4(p0, a0.z, w);
  w = WS[d0+3]; ACC4(p0, a0.w, w);
  w = WS[256+d0+0]; ACC4(p1, a1.x, w);
  w = WS[256+d0+1]; ACC4(p1, a1.y, w);
  w = WS[256+d0+2]; ACC4(p1, a1.z, w);
  w = WS[256+d0+3]; ACC4(p1, a1.w, w);
  w = WD[d0+0]; ACC4(q0, ad.x, w);
  w = WD[d0+1]; ACC4(q0, ad.y, w);
  w = WD[d0+2]; ACC4(q0, ad.z, w);
  w = WD[d0+3]; ACC4(q0, ad.w, w);
  w = WD[256+d0+0]; ACC4(q1, ad.x, w);
  w = WD[256+d0+1]; ACC4(q1, ad.y, w);
  w = WD[256+d0+2]; ACC4(q1, ad.z, w);
  w = WD[256+d0+3]; ACC4(q1, ad.w, w);
  p0 = wred_sum4(p0); p1 = wred_sum4(p1); q0 = wred_sum4(q0); q1 = wred_sum4(q1);
  float4 sb0 = *(const float4*)(semS_b + 0);
  float4 sb1 = *(const float4*)(semS_b + 4);
  float4 db0 = *(const float4*)(semD_b + 0);
  float4 db1 = *(const float4*)(semD_b + 4);
  float4 s0, s1;
  s0.x = lrelu(p0.x*i0 + sb0.x + q0.x*idn + db0.x);
  s0.y = lrelu(p0.y*i0 + sb0.y + q0.y*idn + db0.y);
  s0.z = lrelu(p0.z*i0 + sb0.z + q0.z*idn + db0.z);
  s0.w = lrelu(p0.w*i0 + sb0.w + q0.w*idn + db0.w);
  s1.x = lrelu(p1.x*i1 + sb1.x + q1.x*idn + db1.x);
  s1.y = lrelu(p1.y*i1 + sb1.y + q1.y*idn + db1.y);
  s1.z = lrelu(p1.z*i1 + sb1.z + q1.z*idn + db1.z);
  s1.w = lrelu(p1.w*i1 + sb1.w + q1.w*idn + db1.w);
  float4 at0, at1;
  sm2(s0.x, s1.x, relw[0], relw[4], at0.x, at1.x);
  sm2(s0.y, s1.y, relw[1], relw[5], at0.y, at1.y);
  sm2(s0.z, s1.z, relw[2], relw[6], at0.z, at1.z);
  sm2(s0.w, s1.w, relw[3], relw[7], at0.w, at1.w);
  float w0 = h==0 ? at0.x : h==1 ? at0.y : h==2 ? at0.z : at0.w;
  float w1 = h==0 ? at1.x : h==1 ? at1.y : h==2 ? at1.z : at1.w;
  float4 x;
  x.x = fmaf(a0.x, w0, fmaf(a1.x, w1, ha.x));
  x.y = fmaf(a0.y, w0, fmaf(a1.y, w1, ha.y));
  x.z = fmaf(a0.z, w0, fmaf(a1.z, w1, ha.z));
  x.w = fmaf(a0.w, w0, fmaf(a1.w, w1, ha.w));
  float4 g;
  g.x = gelu_exact(x.x); g.y = gelu_exact(x.y); g.z = gelu_exact(x.z); g.w = gelu_exact(x.w);
  float ng = wred_sum(g.x*g.x + g.y*g.y + g.z*g.z + g.w*g.w);
  float inv = 1.f / fmaxf(sqrtf(ng), 1e-9f);
  g.x *= inv; g.y *= inv; g.z *= inv; g.w *= inv;
  ((float4*)hd_io)[(size_t)n*64 + lane] = g;
}

// Node type B fallback: out_B = normalize(gelu(nb + h_B)); nb lives in outB region.
__global__ __launch_bounds__(256) void fusionB_kernel(float* __restrict__ outB,
                                                      const float* __restrict__ hB, int N)
{
  int n = blockIdx.x*4 + (threadIdx.x >> 6);
  if (n >= N) return;
  int lane = threadIdx.x & 63;
  float4 x = ((float4*)outB)[(size_t)n*64 + lane];
  float4 b = ((const float4*)hB)[(size_t)n*64 + lane];
  x.x += b.x; x.y += b.y; x.z += b.z; x.w += b.w;
  float4 g;
  g.x = gelu_exact(x.x); g.y = gelu_exact(x.y); g.z = gelu_exact(x.z); g.w = gelu_exact(x.w);
  float ng = wred_sum(g.x*g.x + g.y*g.y + g.z*g.z + g.w*g.w);
  float inv = 1.f / fmaxf(sqrtf(ng), 1e-9f);
  g.x *= inv; g.y *= inv; g.z *= inv; g.w *= inv;
  ((float4*)outB)[(size_t)n*64 + lane] = g;
}

// ---------------------------------------------------------------------------
extern "C" void kernel_launch(void* const* d_in, const int* in_sizes, int n_in,
                              void* d_out, int out_size, void* d_ws, size_t ws_size,
                              hipStream_t stream)
{
  const float* hA     = (const float*)d_in[0];
  const float* hB     = (const float*)d_in[1];
  const int*   src0   = (const int*)d_in[2];
  const int*   dst0   = (const int*)d_in[3];
  const int*   src1   = (const int*)d_in[4];
  const int*   dst1   = (const int*)d_in[5];
  const float* node_W = (const float*)d_in[6];
  const float* node_b = (const float*)d_in[7];
  const float* edge_W = (const float*)d_in[8];
  const float* edge_b = (const float*)d_in[9];
  const float* srcA_W = (const float*)d_in[10];
  const float* srcA_b = (const float*)d_in[11];
  const float* dstA_W = (const float*)d_in[12];
  const float* dstA_b = (const float*)d_in[13];
  const float* semS_W = (const float*)d_in[14];
  const float* semS_b = (const float*)d_in[15];
  const float* semD_W = (const float*)d_in[16];
  const float* semD_b = (const float*)d_in[17];
  const float* relA_W = (const float*)d_in[18];
  const float* relA_b = (const float*)d_in[19];
  const float* rel_emb= (const float*)d_in[20];

  const int N = in_sizes[0] / D;
  const int E = in_sizes[2];

  float* out  = (float*)d_out;
  float* outA = out;                    // scratch for hd (=z_dst), then final out_A
  float* outB = out + (size_t)N*D;      // scratch for nb, then final out_B

  float* w = (float*)d_ws;
  float* hs0  = w; w += (size_t)N*D;
  float* hs1  = w; w += (size_t)N*D;
  float* as0  = w; w += (size_t)N*HN;
  float* as1  = w; w += (size_t)N*HN;
  float* ad0  = w; w += (size_t)N*HN;
  float* ad1  = w; w += (size_t)N*HN;
  float* relw = w; w += 16;
  __bf16* WtHi = (__bf16*)w; w += 131072;   // 4 mats * 65536 bf16 = 512KB
  __bf16* WtLo = (__bf16*)w; w += 131072;
  int* ip   = (int*)w;
  int* cnt0 = ip; ip += N;
  int* cnt1 = ip; ip += N;
  int* rp0  = ip; ip += N+1;
  int* rp1  = ip; ip += N+1;
  int* cur0 = ip; ip += N;
  int* cur1 = ip; ip += N;
  int* part0= ip; ip += 256;
  int* part1= ip; ip += 256;
  int* csr0 = ip; ip += E;
  int* csr1 = ip; ip += E;

  const int nwb = (N + 3) / 4;

  // weight transpose + bf16 hi/lo split
  wt_setup<<<1024, 256, 0, stream>>>(node_W, edge_W, WtHi, WtLo);

  // 4 GEMMs batched in one launch (grid.z selects matrix)
  dim3 ggrid((N + 127)/128, 2, 4);
  gemm_mfma4<<<ggrid, 256, 0, stream>>>(hA, hB, WtHi, WtLo, node_b, edge_b,
                                        outA, hs0, hs1, outB, N);

  attn_vec_kernel<<<nwb, 256, 0, stream>>>(hs0, hs1, outA, srcA_W, srcA_b, dstA_W, dstA_b,
                                           as0, as1, ad0, ad1, N);
  rel_kernel<<<1, 64, 0, stream>>>(rel_emb, relA_W, relA_b, relw);

  // CSR build for both relations
  zero_int<<<(2*N + 255)/256, 256, 0, stream>>>(cnt0, 2*N);
  hist_kernel<<<(E + 255)/256, 256, 0, stream>>>(dst0, dst1, cnt0, cnt1, E);
  const int nchunk = (N + 1023)/1024;
  dim3 sgrid(nchunk, 2);
  scan1<<<sgrid, 1024, 0, stream>>>(cnt0, cnt1, rp0, rp1, part0, part1, N);
  scan2<<<1, 64, 0, stream>>>(part0, part1, nchunk, rp0 + N, rp1 + N);
  scan3<<<sgrid, 1024, 0, stream>>>(rp0, rp1, cur0, cur1, part0, part1, N);
  scatter_kernel<<<(E + 255)/256, 256, 0, stream>>>(src0, dst0, cur0, csr0,
                                                    src1, dst1, cur1, csr1, E);

  // fused aggregation v2: wave per (node, relation) + fusion epilogue
  aggregate_fused2<<<(N + 1)/2, 256, 0, stream>>>(rp0, csr0, as0, ad0, hs0,
                                                  rp1, csr1, as1, ad1, hs1,
                                                  outA, hA, semS_W, semS_b, semD_W, semD_b,
                                                  relw, N);

  fusionB_kernel<<<nwb, 256, 0, stream>>>(outB, hB, N);
}

// Round 12
// 596.707 us; speedup vs baseline: 1.5795x; 1.0550x over previous
//
#include <hip/hip_runtime.h>
#include <math.h>

#define D 256
#define HN 4
#define HT 4

typedef __bf16 bf16x8 __attribute__((ext_vector_type(8)));
typedef float  f32x16 __attribute__((ext_vector_type(16)));

__device__ __forceinline__ float lrelu(float x){ return x > 0.f ? x : 0.01f*x; }
__device__ __forceinline__ float gelu_exact(float x){ return 0.5f*x*(1.f+erff(x*0.70710678118654752f)); }

__device__ __forceinline__ float wred_sum(float v){
#pragma unroll
  for (int o = 32; o > 0; o >>= 1) v += __shfl_xor(v, o);
  return v;
}
__device__ __forceinline__ float4 wred_sum4(float4 v){
  v.x = wred_sum(v.x); v.y = wred_sum(v.y); v.z = wred_sum(v.z); v.w = wred_sum(v.w);
  return v;
}

#define ACC4(p, s, w) do { (p).x = fmaf((s),(w).x,(p).x); (p).y = fmaf((s),(w).y,(p).y); \
                           (p).z = fmaf((s),(w).z,(p).z); (p).w = fmaf((s),(w).w,(p).w); } while(0)

// ---------------------------------------------------------------------------
// Weight prep: tiled layout matching the GEMM's LDS DMA order.
// WtHi/Lo[mat][ks=k/8][n][j=k%8] : chunk (ks, n-range) is contiguous -> the
// GEMM stages W with contiguous 1KB global_load_lds transfers.
// mats: 0=node_W[0], 1=node_W[1], 2=edge_W[0], 3=edge_W[1]
// ---------------------------------------------------------------------------
__global__ void wt_setup(const float* __restrict__ nodeW, const float* __restrict__ edgeW,
                         __bf16* __restrict__ WtHi, __bf16* __restrict__ WtLo)
{
  int t = blockIdx.x*256 + threadIdx.x;     // 4 mats * 32 ks * 256 n = 32768
  int mat = t >> 13;
  int r   = t & 8191;
  int ks  = r >> 8;        // 0..31  (8-k group)
  int n   = r & 255;       // output col
  const float* src = (mat==0)? nodeW : (mat==1)? nodeW+65536 : (mat==2)? edgeW : edgeW+65536;
  bf16x8 hi, lo;
#pragma unroll
  for (int j = 0; j < 8; ++j){
    float x = src[(size_t)(ks*8 + j)*256 + n];
    __bf16 h = (__bf16)x;
    hi[j] = h;
    lo[j] = (__bf16)(x - (float)h);
  }
  size_t o = (size_t)mat*65536 + ((size_t)ks*256 + n)*8;
  *(bf16x8*)(WtHi + o) = hi;
  *(bf16x8*)(WtLo + o) = lo;
}

// ---------------------------------------------------------------------------
// Batched 4-GEMM v3: C[M x 256] = A[M x 256] @ W + bias, split-bf16 3-term.
// BM=128, BN=256 (full width -> A staged once), BK=32, 512 threads (8 waves,
// 2x4 of 64x64 wave tiles). W staged via global_load_lds (async DMA, zero
// registers); A reg-staged with fp32->bf16 hi/lo conversion.
// LDS: A_hi@0 A_lo@8256 (slot stride 2064), W_hi@16512 W_lo@32960 (slot
// stride 4112). Total 49408 B.
// ---------------------------------------------------------------------------
__device__ __forceinline__ void cvt8(const float4 a, const float4 b, bf16x8& h, bf16x8& l){
  float v0=a.x,v1=a.y,v2=a.z,v3=a.w,v4=b.x,v5=b.y,v6=b.z,v7=b.w;
  __bf16 t;
  t=(__bf16)v0; h[0]=t; l[0]=(__bf16)(v0-(float)t);
  t=(__bf16)v1; h[1]=t; l[1]=(__bf16)(v1-(float)t);
  t=(__bf16)v2; h[2]=t; l[2]=(__bf16)(v2-(float)t);
  t=(__bf16)v3; h[3]=t; l[3]=(__bf16)(v3-(float)t);
  t=(__bf16)v4; h[4]=t; l[4]=(__bf16)(v4-(float)t);
  t=(__bf16)v5; h[5]=t; l[5]=(__bf16)(v5-(float)t);
  t=(__bf16)v6; h[6]=t; l[6]=(__bf16)(v6-(float)t);
  t=(__bf16)v7; h[7]=t; l[7]=(__bf16)(v7-(float)t);
}

#define MFMA32 __builtin_amdgcn_mfma_f32_32x32x16_bf16

__global__ __launch_bounds__(512, 4) void gemm_mfma4(
    const float* __restrict__ hA, const float* __restrict__ hB,
    const __bf16* __restrict__ WtHi, const __bf16* __restrict__ WtLo,
    const float* __restrict__ node_b, const float* __restrict__ edge_b,
    float* __restrict__ outA, float* __restrict__ hs0,
    float* __restrict__ hs1, float* __restrict__ outB, int M)
{
  const int z = blockIdx.y;
  const float* A    = (z==0)? hA : hB;
  const int    mat  = (z==0)? 0 : (z==1)? 2 : (z==2)? 3 : 1;
  const float* bias = (z==0)? node_b : (z==1)? edge_b : (z==2)? edge_b+256 : node_b+256;
  float*       C    = (z==0)? outA : (z==1)? hs0 : (z==2)? hs1 : outB;
  const __bf16* Wh  = WtHi + (size_t)mat*65536;
  const __bf16* Wl  = WtLo + (size_t)mat*65536;

  __shared__ __align__(16) char smem[49408];
  const int tid  = threadIdx.x;
  const int bm   = blockIdx.x * 128;
  const int lane = tid & 63;
  const int wid  = tid >> 6;       // 0..7
  const int wm   = wid >> 2;       // 0..1  rows wm*64
  const int wn   = wid & 3;        // 0..3  cols wn*64

  f32x16 acc[2][2] = {};

  // A staging: thread -> (row = tid>>2, slot = tid&3); 8 k-elems per thread
  const int a_row  = tid >> 2;     // 0..127
  const int a_slot = tid & 3;
  int arow = bm + a_row; if (arow >= M) arow = M - 1;
  const float* gA = A + (size_t)arow*256 + a_slot*8;
  const int a_wr = a_slot*2064 + a_row*16;

  float4 f0, f1;
  f0 = *(const float4*)(gA + 0);
  f1 = *(const float4*)(gA + 4);

  for (int it = 0; it < 8; ++it) {
    bf16x8 hh, ll;
    cvt8(f0, f1, hh, ll);
    __syncthreads();                       // previous iteration's LDS reads done
    *(bf16x8*)(smem +         a_wr) = hh;
    *(bf16x8*)(smem +  8256 + a_wr) = ll;
    // async W DMA: wave wid stages 4 contiguous-1KB chunks of this K-tile
#pragma unroll
    for (int c = 0; c < 4; ++c) {
      int ch     = wid*4 + c;              // 0..31
      int region = ch >> 4;                // 0=hi 1=lo
      int slot   = (ch >> 2) & 3;
      int half   = ch & 3;                 // 64-row group of the 256 cols
      const __bf16* gsrc = (region ? Wl : Wh)
                         + ((size_t)((it*4 + slot)*256 + half*64)*8) + (size_t)lane*8;
      char* ldst = smem + 16512 + region*16448 + slot*4112 + half*1024;
      __builtin_amdgcn_global_load_lds(
          (const __attribute__((address_space(1))) void*)gsrc,
          (__attribute__((address_space(3))) void*)ldst, 16, 0, 0);
    }
    __syncthreads();                       // vmcnt(0) drain: DMA + A writes visible
    if (it < 7) {                          // A prefetch overlaps MFMA below
      f0 = *(const float4*)(gA + (it+1)*32 + 0);
      f1 = *(const float4*)(gA + (it+1)*32 + 4);
    }
#pragma unroll
    for (int ks = 0; ks < 2; ++ks) {
      const int sA =         (ks*2 + (lane>>5))*2064 + (lane&31)*16;
      const int sW = 16512 + (ks*2 + (lane>>5))*4112 + (lane&31)*16;
      bf16x8 aH0 = *(const bf16x8*)(smem +        sA + (wm*64    )*16);
      bf16x8 aH1 = *(const bf16x8*)(smem +        sA + (wm*64+32 )*16);
      bf16x8 aL0 = *(const bf16x8*)(smem + 8256 + sA + (wm*64    )*16);
      bf16x8 aL1 = *(const bf16x8*)(smem + 8256 + sA + (wm*64+32 )*16);
      bf16x8 bH0 = *(const bf16x8*)(smem +         sW + (wn*64    )*16);
      bf16x8 bH1 = *(const bf16x8*)(smem +         sW + (wn*64+32 )*16);
      bf16x8 bL0 = *(const bf16x8*)(smem + 16448 + sW + (wn*64    )*16);
      bf16x8 bL1 = *(const bf16x8*)(smem + 16448 + sW + (wn*64+32 )*16);
      acc[0][0] = MFMA32(aH0,bH0,acc[0][0],0,0,0);
      acc[0][0] = MFMA32(aH0,bL0,acc[0][0],0,0,0);
      acc[0][0] = MFMA32(aL0,bH0,acc[0][0],0,0,0);
      acc[0][1] = MFMA32(aH0,bH1,acc[0][1],0,0,0);
      acc[0][1] = MFMA32(aH0,bL1,acc[0][1],0,0,0);
      acc[0][1] = MFMA32(aL0,bH1,acc[0][1],0,0,0);
      acc[1][0] = MFMA32(aH1,bH0,acc[1][0],0,0,0);
      acc[1][0] = MFMA32(aH1,bL0,acc[1][0],0,0,0);
      acc[1][0] = MFMA32(aL1,bH0,acc[1][0],0,0,0);
      acc[1][1] = MFMA32(aH1,bH1,acc[1][1],0,0,0);
      acc[1][1] = MFMA32(aH1,bL1,acc[1][1],0,0,0);
      acc[1][1] = MFMA32(aL1,bH1,acc[1][1],0,0,0);
    }
  }

  // epilogue: +bias, scalar stores (coalesced per reg across lanes 0..31)
#pragma unroll
  for (int fn = 0; fn < 2; ++fn) {
    const int col = wn*64 + fn*32 + (lane&31);
    float bval = bias[col];
#pragma unroll
    for (int fm = 0; fm < 2; ++fm) {
      int rbase = bm + wm*64 + fm*32 + 4*(lane>>5);
#pragma unroll
      for (int r = 0; r < 16; ++r) {
        int row = rbase + (r&3) + 8*(r>>2);
        if (row < M) C[(size_t)row*256 + col] = acc[fm][fn][r] + bval;
      }
    }
  }
}

// ---------------------------------------------------------------------------
// Per-node attention projections.
// ---------------------------------------------------------------------------
__global__ __launch_bounds__(256) void attn_vec_kernel(
    const float* __restrict__ hs0, const float* __restrict__ hs1,
    const float* __restrict__ hd,
    const float* __restrict__ srcA_W, const float* __restrict__ srcA_b,
    const float* __restrict__ dstA_W, const float* __restrict__ dstA_b,
    float* __restrict__ as0, float* __restrict__ as1,
    float* __restrict__ ad0, float* __restrict__ ad1, int N)
{
  int n = blockIdx.x*4 + (threadIdx.x >> 6);
  if (n >= N) return;
  int lane = threadIdx.x & 63;
  int d0 = lane << 2;
  const float4* Ws = (const float4*)srcA_W;
  const float4* Wd = (const float4*)dstA_W;
  float4 r0 = ((const float4*)hs0)[(size_t)n*64 + lane];
  float4 r1 = ((const float4*)hs1)[(size_t)n*64 + lane];
  float4 rd = ((const float4*)hd )[(size_t)n*64 + lane];
  float4 p0 = make_float4(0,0,0,0), p1 = make_float4(0,0,0,0);
  float4 q0 = make_float4(0,0,0,0), q1 = make_float4(0,0,0,0);
  float4 w;
  w = Ws[d0+0]; ACC4(p0, r0.x, w);
  w = Ws[d0+1]; ACC4(p0, r0.y, w);
  w = Ws[d0+2]; ACC4(p0, r0.z, w);
  w = Ws[d0+3]; ACC4(p0, r0.w, w);
  w = Ws[256+d0+0]; ACC4(p1, r1.x, w);
  w = Ws[256+d0+1]; ACC4(p1, r1.y, w);
  w = Ws[256+d0+2]; ACC4(p1, r1.z, w);
  w = Ws[256+d0+3]; ACC4(p1, r1.w, w);
  w = Wd[d0+0]; ACC4(q0, rd.x, w);
  w = Wd[d0+1]; ACC4(q0, rd.y, w);
  w = Wd[d0+2]; ACC4(q0, rd.z, w);
  w = Wd[d0+3]; ACC4(q0, rd.w, w);
  w = Wd[256+d0+0]; ACC4(q1, rd.x, w);
  w = Wd[256+d0+1]; ACC4(q1, rd.y, w);
  w = Wd[256+d0+2]; ACC4(q1, rd.z, w);
  w = Wd[256+d0+3]; ACC4(q1, rd.w, w);
  p0 = wred_sum4(p0); p1 = wred_sum4(p1); q0 = wred_sum4(q0); q1 = wred_sum4(q1);
  if (lane == 0) {
    float4 b;
    b = *(const float4*)(srcA_b + 0);
    ((float4*)as0)[n] = make_float4(p0.x+b.x, p0.y+b.y, p0.z+b.z, p0.w+b.w);
    b = *(const float4*)(srcA_b + 4);
    ((float4*)as1)[n] = make_float4(p1.x+b.x, p1.y+b.y, p1.z+b.z, p1.w+b.w);
    b = *(const float4*)(dstA_b + 0);
    ((float4*)ad0)[n] = make_float4(q0.x+b.x, q0.y+b.y, q0.z+b.z, q0.w+b.w);
    b = *(const float4*)(dstA_b + 4);
    ((float4*)ad1)[n] = make_float4(q1.x+b.x, q1.y+b.y, q1.z+b.z, q1.w+b.w);
  }
}

// rel attention (node-invariant), pre-scaled by (1-ALPHA)=0.5
__global__ void rel_kernel(const float* __restrict__ rel_emb, const float* __restrict__ relA_W,
                           const float* __restrict__ relA_b, float* __restrict__ rel_out)
{
  int t = threadIdx.x;
  if (t < 8) {
    int r = t >> 2, h = t & 3;
    float s = relA_b[r*4+h];
    for (int d = 0; d < 256; ++d)
      s = fmaf(rel_emb[r*256+d], relA_W[(size_t)(r*256+d)*4+h], s);
    s = lrelu(s);
    float other = __shfl_xor(s, 4);
    float mm = fmaxf(s, other);
    float e  = expf(s - mm), eo = expf(other - mm);
    rel_out[r*4+h] = 0.5f * e / (e + eo);
  }
}

// ---------------------------------------------------------------------------
// CSR build helpers
// ---------------------------------------------------------------------------
__global__ void zero_int(int* p, int n){
  int i = blockIdx.x*blockDim.x + threadIdx.x;
  if (i < n) p[i] = 0;
}

__global__ void hist_kernel(const int* __restrict__ dst0, const int* __restrict__ dst1,
                            int* c0, int* c1, int E){
  int e = blockIdx.x*256 + threadIdx.x;
  if (e < E) { atomicAdd(&c0[dst0[e]], 1); atomicAdd(&c1[dst1[e]], 1); }
}

__global__ __launch_bounds__(1024) void scan1(const int* __restrict__ cnt0, const int* __restrict__ cnt1,
                                              int* __restrict__ rp0, int* __restrict__ rp1,
                                              int* __restrict__ part0, int* __restrict__ part1, int n){
  const int* cnt = blockIdx.y ? cnt1 : cnt0;
  int* excl = blockIdx.y ? rp1 : rp0;
  int* part = blockIdx.y ? part1 : part0;
  __shared__ int sm[1024];
  int tid = threadIdx.x;
  int gid = blockIdx.x*1024 + tid;
  int v = (gid < n) ? cnt[gid] : 0;
  sm[tid] = v; __syncthreads();
  for (int off = 1; off < 1024; off <<= 1){
    int t = sm[tid];
    if (tid >= off) t += sm[tid-off];
    __syncthreads();
    sm[tid] = t; __syncthreads();
  }
  if (gid < n) excl[gid] = sm[tid] - v;
  if (tid == 1023) part[blockIdx.x] = sm[1023];
}

__global__ void scan2(int* part0, int* part1, int nchunk, int* tot0, int* tot1){
  if (threadIdx.x == 0 && blockIdx.x == 0){
    int run = 0;
    for (int i = 0; i < nchunk; ++i){ int t = part0[i]; part0[i] = run; run += t; }
    *tot0 = run;
    run = 0;
    for (int i = 0; i < nchunk; ++i){ int t = part1[i]; part1[i] = run; run += t; }
    *tot1 = run;
  }
}

__global__ __launch_bounds__(1024) void scan3(int* __restrict__ rp0, int* __restrict__ rp1,
                                              int* __restrict__ cur0, int* __restrict__ cur1,
                                              const int* __restrict__ part0, const int* __restrict__ part1, int n){
  int* rp  = blockIdx.y ? rp1 : rp0;
  int* cur = blockIdx.y ? cur1 : cur0;
  const int* part = blockIdx.y ? part1 : part0;
  int gid = blockIdx.x*1024 + threadIdx.x;
  if (gid < n){ int v = rp[gid] + part[blockIdx.x]; rp[gid] = v; cur[gid] = v; }
}

__global__ void scatter_kernel(const int* __restrict__ src0, const int* __restrict__ dst0,
                               int* cur0, int* __restrict__ csr0,
                               const int* __restrict__ src1, const int* __restrict__ dst1,
                               int* cur1, int* __restrict__ csr1, int E){
  int e = blockIdx.x*256 + threadIdx.x;
  if (e < E){
    int p = atomicAdd(&cur0[dst0[e]], 1); csr0[p] = src0[e];
    p = atomicAdd(&cur1[dst1[e]], 1); csr1[p] = src1[e];
  }
}

// ---------------------------------------------------------------------------
// Fused aggregation v2: one wave per (node,relation), single pass per edge,
// LDS exchange, fusion epilogue on rel0 wave.
// ---------------------------------------------------------------------------
__device__ __forceinline__ void sm2(float s0, float s1, float r0, float r1, float& o0, float& o1){
  float mm = fmaxf(s0, s1);
  float e0 = expf(s0-mm), e1 = expf(s1-mm);
  float inv = 1.f/(e0+e1);
  o0 = fmaf(0.5f*e0, inv, r0);
  o1 = fmaf(0.5f*e1, inv, r1);
}

__global__ __launch_bounds__(256) void aggregate_fused2(
    const int* __restrict__ rp0, const int* __restrict__ csr0,
    const float* __restrict__ as0, const float* __restrict__ ad0,
    const float* __restrict__ hs0,
    const int* __restrict__ rp1, const int* __restrict__ csr1,
    const float* __restrict__ as1, const float* __restrict__ ad1,
    const float* __restrict__ hs1,
    float* __restrict__ hd_io, const float* __restrict__ hA,
    const float* __restrict__ semS_W, const float* __restrict__ semS_b,
    const float* __restrict__ semD_W, const float* __restrict__ semD_b,
    const float* __restrict__ relw, int N)
{
  __shared__ float4 a1_lds[2][64];
  const int tid    = threadIdx.x;
  const int lane   = tid & 63;
  const int wid    = tid >> 6;
  const int locn   = wid >> 1;       // 0/1: node within block
  const int rel    = wid & 1;        // 0/1: relation
  const int n      = blockIdx.x*2 + locn;
  const int h      = lane >> 4;
  const bool active = (n < N);

  float4 acc = make_float4(0.f,0.f,0.f,0.f);
  if (active) {
    const int*   rp  = rel ? rp1  : rp0;
    const int*   csr = rel ? csr1 : csr0;
    const float* as  = rel ? as1  : as0;
    const float* ad  = rel ? ad1  : ad0;
    const float* hs  = rel ? hs1  : hs0;
    int start = rp[n];
    int cnt   = rp[n+1] - start;
    if (cnt > 0) {
      float adh = ad[(size_t)n*4 + h];
      const float4* hsv = (const float4*)hs;
      float ssum = 0.f;
      int i = 0;
      for (; i+4 <= cnt; i += 4) {
        int s0 = csr[start+i], s1 = csr[start+i+1], s2 = csr[start+i+2], s3 = csr[start+i+3];
        float w0 = __expf(lrelu(as[(size_t)s0*4+h] + adh));
        float w1 = __expf(lrelu(as[(size_t)s1*4+h] + adh));
        float w2 = __expf(lrelu(as[(size_t)s2*4+h] + adh));
        float w3 = __expf(lrelu(as[(size_t)s3*4+h] + adh));
        float4 v0 = hsv[(size_t)s0*64 + lane];
        float4 v1 = hsv[(size_t)s1*64 + lane];
        float4 v2 = hsv[(size_t)s2*64 + lane];
        float4 v3 = hsv[(size_t)s3*64 + lane];
        acc.x = fmaf(v0.x,w0,acc.x); acc.y = fmaf(v0.y,w0,acc.y);
        acc.z = fmaf(v0.z,w0,acc.z); acc.w = fmaf(v0.w,w0,acc.w);
        acc.x = fmaf(v1.x,w1,acc.x); acc.y = fmaf(v1.y,w1,acc.y);
        acc.z = fmaf(v1.z,w1,acc.z); acc.w = fmaf(v1.w,w1,acc.w);
        acc.x = fmaf(v2.x,w2,acc.x); acc.y = fmaf(v2.y,w2,acc.y);
        acc.z = fmaf(v2.z,w2,acc.z); acc.w = fmaf(v2.w,w2,acc.w);
        acc.x = fmaf(v3.x,w3,acc.x); acc.y = fmaf(v3.y,w3,acc.y);
        acc.z = fmaf(v3.z,w3,acc.z); acc.w = fmaf(v3.w,w3,acc.w);
        ssum += w0 + w1 + w2 + w3;
      }
      for (; i < cnt; ++i) {
        int s = csr[start+i];
        float wv = __expf(lrelu(as[(size_t)s*4+h] + adh));
        float4 v = hsv[(size_t)s*64 + lane];
        acc.x = fmaf(v.x,wv,acc.x); acc.y = fmaf(v.y,wv,acc.y);
        acc.z = fmaf(v.z,wv,acc.z); acc.w = fmaf(v.w,wv,acc.w);
        ssum += wv;
      }
      float inv = 1.f / ssum;
      acc.x *= inv; acc.y *= inv; acc.z *= inv; acc.w *= inv;
    }
  }
  if (rel == 1) a1_lds[locn][lane] = acc;
  __syncthreads();
  if (rel == 1 || !active) return;

  // ---- fusion epilogue (rel0 wave of each node) ----
  float4 a0 = acc;
  float4 a1 = a1_lds[locn][lane];
  int d0 = lane << 2;
  float4 ad = ((float4*)hd_io)[(size_t)n*64 + lane];   // z_dst row
  float4 ha = ((const float4*)hA)[(size_t)n*64 + lane];
  float nz0 = wred_sum(a0.x*a0.x + a0.y*a0.y + a0.z*a0.z + a0.w*a0.w);
  float nz1 = wred_sum(a1.x*a1.x + a1.y*a1.y + a1.z*a1.z + a1.w*a1.w);
  float nzd = wred_sum(ad.x*ad.x + ad.y*ad.y + ad.z*ad.z + ad.w*ad.w);
  float i0  = 1.f / fmaxf(sqrtf(nz0), 1e-9f);
  float i1  = 1.f / fmaxf(sqrtf(nz1), 1e-9f);
  float idn = 1.f / fmaxf(sqrtf(nzd), 1e-9f);
  const float4* WS = (const float4*)semS_W;
  const float4* WD = (const float4*)semD_W;
  float4 p0 = make_float4(0,0,0,0), p1 = make_float4(0,0,0,0);
  float4 q0 = make_float4(0,0,0,0), q1 = make_float4(0,0,0,0);
  float4 w;
  w = WS[d0+0]; ACC4(p0, a0.x, w);
  w = WS[d0+1]; ACC4(p0, a0.y, w);
  w = WS[d0+2]; ACC4(p0, a0.z, w);
  w = WS[d0+3]; ACC4(p0, a0.w, w);
  w = WS[256+d0+0]; ACC4(p1, a1.x, w);
  w = WS[256+d0+1]; ACC4(p1, a1.y, w);
  w = WS[256+d0+2]; ACC4(p1, a1.z, w);
  w = WS[256+d0+3]; ACC4(p1, a1.w, w);
  w = WD[d0+0]; ACC4(q0, ad.x, w);
  w = WD[d0+1]; ACC4(q0, ad.y, w);
  w = WD[d0+2]; ACC4(q0, ad.z, w);
  w = WD[d0+3]; ACC4(q0, ad.w, w);
  w = WD[256+d0+0]; ACC4(q1, ad.x, w);
  w = WD[256+d0+1]; ACC4(q1, ad.y, w);
  w = WD[256+d0+2]; ACC4(q1, ad.z, w);
  w = WD[256+d0+3]; ACC4(q1, ad.w, w);
  p0 = wred_sum4(p0); p1 = wred_sum4(p1); q0 = wred_sum4(q0); q1 = wred_sum4(q1);
  float4 sb0 = *(const float4*)(semS_b + 0);
  float4 sb1 = *(const float4*)(semS_b + 4);
  float4 db0 = *(const float4*)(semD_b + 0);
  float4 db1 = *(const float4*)(semD_b + 4);
  float4 s0, s1;
  s0.x = lrelu(p0.x*i0 + sb0.x + q0.x*idn + db0.x);
  s0.y = lrelu(p0.y*i0 + sb0.y + q0.y*idn + db0.y);
  s0.z = lrelu(p0.z*i0 + sb0.z + q0.z*idn + db0.z);
  s0.w = lrelu(p0.w*i0 + sb0.w + q0.w*idn + db0.w);
  s1.x = lrelu(p1.x*i1 + sb1.x + q1.x*idn + db1.x);
  s1.y = lrelu(p1.y*i1 + sb1.y + q1.y*idn + db1.y);
  s1.z = lrelu(p1.z*i1 + sb1.z + q1.z*idn + db1.z);
  s1.w = lrelu(p1.w*i1 + sb1.w + q1.w*idn + db1.w);
  float4 at0, at1;
  sm2(s0.x, s1.x, relw[0], relw[4], at0.x, at1.x);
  sm2(s0.y, s1.y, relw[1], relw[5], at0.y, at1.y);
  sm2(s0.z, s1.z, relw[2], relw[6], at0.z, at1.z);
  sm2(s0.w, s1.w, relw[3], relw[7], at0.w, at1.w);
  float w0 = h==0 ? at0.x : h==1 ? at0.y : h==2 ? at0.z : at0.w;
  float w1 = h==0 ? at1.x : h==1 ? at1.y : h==2 ? at1.z : at1.w;
  float4 x;
  x.x = fmaf(a0.x, w0, fmaf(a1.x, w1, ha.x));
  x.y = fmaf(a0.y, w0, fmaf(a1.y, w1, ha.y));
  x.z = fmaf(a0.z, w0, fmaf(a1.z, w1, ha.z));
  x.w = fmaf(a0.w, w0, fmaf(a1.w, w1, ha.w));
  float4 g;
  g.x = gelu_exact(x.x); g.y = gelu_exact(x.y); g.z = gelu_exact(x.z); g.w = gelu_exact(x.w);
  float ng = wred_sum(g.x*g.x + g.y*g.y + g.z*g.z + g.w*g.w);
  float inv = 1.f / fmaxf(sqrtf(ng), 1e-9f);
  g.x *= inv; g.y *= inv; g.z *= inv; g.w *= inv;
  ((float4*)hd_io)[(size_t)n*64 + lane] = g;
}

// Node type B fallback: out_B = normalize(gelu(nb + h_B)); nb lives in outB region.
__global__ __launch_bounds__(256) void fusionB_kernel(float* __restrict__ outB,
                                                      const float* __restrict__ hB, int N)
{
  int n = blockIdx.x*4 + (threadIdx.x >> 6);
  if (n >= N) return;
  int lane = threadIdx.x & 63;
  float4 x = ((float4*)outB)[(size_t)n*64 + lane];
  float4 b = ((const float4*)hB)[(size_t)n*64 + lane];
  x.x += b.x; x.y += b.y; x.z += b.z; x.w += b.w;
  float4 g;
  g.x = gelu_exact(x.x); g.y = gelu_exact(x.y); g.z = gelu_exact(x.z); g.w = gelu_exact(x.w);
  float ng = wred_sum(g.x*g.x + g.y*g.y + g.z*g.z + g.w*g.w);
  float inv = 1.f / fmaxf(sqrtf(ng), 1e-9f);
  g.x *= inv; g.y *= inv; g.z *= inv; g.w *= inv;
  ((float4*)outB)[(size_t)n*64 + lane] = g;
}

// ---------------------------------------------------------------------------
extern "C" void kernel_launch(void* const* d_in, const int* in_sizes, int n_in,
                              void* d_out, int out_size, void* d_ws, size_t ws_size,
                              hipStream_t stream)
{
  const float* hA     = (const float*)d_in[0];
  const float* hB     = (const float*)d_in[1];
  const int*   src0   = (const int*)d_in[2];
  const int*   dst0   = (const int*)d_in[3];
  const int*   src1   = (const int*)d_in[4];
  const int*   dst1   = (const int*)d_in[5];
  const float* node_W = (const float*)d_in[6];
  const float* node_b = (const float*)d_in[7];
  const float* edge_W = (const float*)d_in[8];
  const float* edge_b = (const float*)d_in[9];
  const float* srcA_W = (const float*)d_in[10];
  const float* srcA_b = (const float*)d_in[11];
  const float* dstA_W = (const float*)d_in[12];
  const float* dstA_b = (const float*)d_in[13];
  const float* semS_W = (const float*)d_in[14];
  const float* semS_b = (const float*)d_in[15];
  const float* semD_W = (const float*)d_in[16];
  const float* semD_b = (const float*)d_in[17];
  const float* relA_W = (const float*)d_in[18];
  const float* relA_b = (const float*)d_in[19];
  const float* rel_emb= (const float*)d_in[20];

  const int N = in_sizes[0] / D;
  const int E = in_sizes[2];

  float* out  = (float*)d_out;
  float* outA = out;                    // scratch for hd (=z_dst), then final out_A
  float* outB = out + (size_t)N*D;      // scratch for nb, then final out_B

  float* w = (float*)d_ws;
  float* hs0  = w; w += (size_t)N*D;
  float* hs1  = w; w += (size_t)N*D;
  float* as0  = w; w += (size_t)N*HN;
  float* as1  = w; w += (size_t)N*HN;
  float* ad0  = w; w += (size_t)N*HN;
  float* ad1  = w; w += (size_t)N*HN;
  float* relw = w; w += 16;
  __bf16* WtHi = (__bf16*)w; w += 131072;   // 4 mats * 65536 bf16 = 512KB
  __bf16* WtLo = (__bf16*)w; w += 131072;
  int* ip   = (int*)w;
  int* cnt0 = ip; ip += N;
  int* cnt1 = ip; ip += N;
  int* rp0  = ip; ip += N+1;
  int* rp1  = ip; ip += N+1;
  int* cur0 = ip; ip += N;
  int* cur1 = ip; ip += N;
  int* part0= ip; ip += 256;
  int* part1= ip; ip += 256;
  int* csr0 = ip; ip += E;
  int* csr1 = ip; ip += E;

  const int nwb = (N + 3) / 4;

  // weight transpose + bf16 hi/lo split (DMA-tile order)
  wt_setup<<<128, 256, 0, stream>>>(node_W, edge_W, WtHi, WtLo);

  // 4 GEMMs batched in one launch (grid.y selects matrix), BN=256 full width
  dim3 ggrid((N + 127)/128, 4);
  gemm_mfma4<<<ggrid, 512, 0, stream>>>(hA, hB, WtHi, WtLo, node_b, edge_b,
                                        outA, hs0, hs1, outB, N);

  attn_vec_kernel<<<nwb, 256, 0, stream>>>(hs0, hs1, outA, srcA_W, srcA_b, dstA_W, dstA_b,
                                           as0, as1, ad0, ad1, N);
  rel_kernel<<<1, 64, 0, stream>>>(rel_emb, relA_W, relA_b, relw);

  // CSR build for both relations
  zero_int<<<(2*N + 255)/256, 256, 0, stream>>>(cnt0, 2*N);
  hist_kernel<<<(E + 255)/256, 256, 0, stream>>>(dst0, dst1, cnt0, cnt1, E);
  const int nchunk = (N + 1023)/1024;
  dim3 sgrid(nchunk, 2);
  scan1<<<sgrid, 1024, 0, stream>>>(cnt0, cnt1, rp0, rp1, part0, part1, N);
  scan2<<<1, 64, 0, stream>>>(part0, part1, nchunk, rp0 + N, rp1 + N);
  scan3<<<sgrid, 1024, 0, stream>>>(rp0, rp1, cur0, cur1, part0, part1, N);
  scatter_kernel<<<(E + 255)/256, 256, 0, stream>>>(src0, dst0, cur0, csr0,
                                                    src1, dst1, cur1, csr1, E);

  // fused aggregation v2: wave per (node, relation) + fusion epilogue
  aggregate_fused2<<<(N + 1)/2, 256, 0, stream>>>(rp0, csr0, as0, ad0, hs0,
                                                  rp1, csr1, as1, ad1, hs1,
                                                  outA, hA, semS_W, semS_b, semD_W, semD_b,
                                                  relw, N);

  fusionB_kernel<<<nwb, 256, 0, stream>>>(outB, hB, N);
}

// Round 13
// 589.077 us; speedup vs baseline: 1.6000x; 1.0130x over previous
//
#include <hip/hip_runtime.h>
#include <math.h>

#define D 256
#define HN 4
#define HT 4

typedef __bf16 bf16x8 __attribute__((ext_vector_type(8)));
typedef __bf16 bf16x4 __attribute__((ext_vector_type(4)));
typedef float  f32x16 __attribute__((ext_vector_type(16)));

__device__ __forceinline__ float lrelu(float x){ return x > 0.f ? x : 0.01f*x; }
__device__ __forceinline__ float gelu_exact(float x){ return 0.5f*x*(1.f+erff(x*0.70710678118654752f)); }

__device__ __forceinline__ float wred_sum(float v){
#pragma unroll
  for (int o = 32; o > 0; o >>= 1) v += __shfl_xor(v, o);
  return v;
}
__device__ __forceinline__ float4 wred_sum4(float4 v){
  v.x = wred_sum(v.x); v.y = wred_sum(v.y); v.z = wred_sum(v.z); v.w = wred_sum(v.w);
  return v;
}

#define ACC4(p, s, w) do { (p).x = fmaf((s),(w).x,(p).x); (p).y = fmaf((s),(w).y,(p).y); \
                           (p).z = fmaf((s),(w).z,(p).z); (p).w = fmaf((s),(w).w,(p).w); } while(0)

// ---------------------------------------------------------------------------
// Weight prep: tiled layout matching the GEMM's LDS DMA order.
// WtHi/Lo[mat][ks=k/8][n][j=k%8]
// mats: 0=node_W[0], 1=node_W[1], 2=edge_W[0], 3=edge_W[1]
// ---------------------------------------------------------------------------
__global__ void wt_setup(const float* __restrict__ nodeW, const float* __restrict__ edgeW,
                         __bf16* __restrict__ WtHi, __bf16* __restrict__ WtLo)
{
  int t = blockIdx.x*256 + threadIdx.x;     // 4 mats * 32 ks * 256 n = 32768
  int mat = t >> 13;
  int r   = t & 8191;
  int ks  = r >> 8;        // 0..31  (8-k group)
  int n   = r & 255;       // output col
  const float* src = (mat==0)? nodeW : (mat==1)? nodeW+65536 : (mat==2)? edgeW : edgeW+65536;
  bf16x8 hi, lo;
#pragma unroll
  for (int j = 0; j < 8; ++j){
    float x = src[(size_t)(ks*8 + j)*256 + n];
    __bf16 h = (__bf16)x;
    hi[j] = h;
    lo[j] = (__bf16)(x - (float)h);
  }
  size_t o = (size_t)mat*65536 + ((size_t)ks*256 + n)*8;
  *(bf16x8*)(WtHi + o) = hi;
  *(bf16x8*)(WtLo + o) = lo;
}

// ---------------------------------------------------------------------------
// Batched 4-GEMM v3: BM=128, BN=256, BK=32, 512 threads (8 waves 2x4).
// W via global_load_lds DMA; A reg-staged with fp32->bf16 hi/lo split.
// z=1,2 (hs0,hs1) store bf16 (halves gather bytes downstream); z=0,3 fp32.
// ---------------------------------------------------------------------------
__device__ __forceinline__ void cvt8(const float4 a, const float4 b, bf16x8& h, bf16x8& l){
  float v0=a.x,v1=a.y,v2=a.z,v3=a.w,v4=b.x,v5=b.y,v6=b.z,v7=b.w;
  __bf16 t;
  t=(__bf16)v0; h[0]=t; l[0]=(__bf16)(v0-(float)t);
  t=(__bf16)v1; h[1]=t; l[1]=(__bf16)(v1-(float)t);
  t=(__bf16)v2; h[2]=t; l[2]=(__bf16)(v2-(float)t);
  t=(__bf16)v3; h[3]=t; l[3]=(__bf16)(v3-(float)t);
  t=(__bf16)v4; h[4]=t; l[4]=(__bf16)(v4-(float)t);
  t=(__bf16)v5; h[5]=t; l[5]=(__bf16)(v5-(float)t);
  t=(__bf16)v6; h[6]=t; l[6]=(__bf16)(v6-(float)t);
  t=(__bf16)v7; h[7]=t; l[7]=(__bf16)(v7-(float)t);
}

#define MFMA32 __builtin_amdgcn_mfma_f32_32x32x16_bf16

__global__ __launch_bounds__(512, 4) void gemm_mfma4(
    const float* __restrict__ hA, const float* __restrict__ hB,
    const __bf16* __restrict__ WtHi, const __bf16* __restrict__ WtLo,
    const float* __restrict__ node_b, const float* __restrict__ edge_b,
    float* __restrict__ outA, __bf16* __restrict__ hs0,
    __bf16* __restrict__ hs1, float* __restrict__ outB, int M)
{
  const int z = blockIdx.y;
  const float* A    = (z==0)? hA : hB;
  const int    mat  = (z==0)? 0 : (z==1)? 2 : (z==2)? 3 : 1;
  const float* bias = (z==0)? node_b : (z==1)? edge_b : (z==2)? edge_b+256 : node_b+256;
  const bool bf16out = (z==1) || (z==2);
  __bf16* Ch = (z==1)? hs0 : hs1;
  float*  Cf = (z==0)? outA : outB;
  const __bf16* Wh  = WtHi + (size_t)mat*65536;
  const __bf16* Wl  = WtLo + (size_t)mat*65536;

  __shared__ __align__(16) char smem[49408];
  const int tid  = threadIdx.x;
  const int bm   = blockIdx.x * 128;
  const int lane = tid & 63;
  const int wid  = tid >> 6;       // 0..7
  const int wm   = wid >> 2;       // 0..1  rows wm*64
  const int wn   = wid & 3;        // 0..3  cols wn*64

  f32x16 acc[2][2] = {};

  const int a_row  = tid >> 2;     // 0..127
  const int a_slot = tid & 3;
  int arow = bm + a_row; if (arow >= M) arow = M - 1;
  const float* gA = A + (size_t)arow*256 + a_slot*8;
  const int a_wr = a_slot*2064 + a_row*16;

  float4 f0, f1;
  f0 = *(const float4*)(gA + 0);
  f1 = *(const float4*)(gA + 4);

  for (int it = 0; it < 8; ++it) {
    bf16x8 hh, ll;
    cvt8(f0, f1, hh, ll);
    __syncthreads();                       // previous iteration's LDS reads done
    *(bf16x8*)(smem +         a_wr) = hh;
    *(bf16x8*)(smem +  8256 + a_wr) = ll;
#pragma unroll
    for (int c = 0; c < 4; ++c) {
      int ch     = wid*4 + c;              // 0..31
      int region = ch >> 4;                // 0=hi 1=lo
      int slot   = (ch >> 2) & 3;
      int half   = ch & 3;
      const __bf16* gsrc = (region ? Wl : Wh)
                         + ((size_t)((it*4 + slot)*256 + half*64)*8) + (size_t)lane*8;
      char* ldst = smem + 16512 + region*16448 + slot*4112 + half*1024;
      __builtin_amdgcn_global_load_lds(
          (const __attribute__((address_space(1))) void*)gsrc,
          (__attribute__((address_space(3))) void*)ldst, 16, 0, 0);
    }
    __syncthreads();                       // vmcnt(0) drain: DMA + A writes visible
    if (it < 7) {
      f0 = *(const float4*)(gA + (it+1)*32 + 0);
      f1 = *(const float4*)(gA + (it+1)*32 + 4);
    }
#pragma unroll
    for (int ks = 0; ks < 2; ++ks) {
      const int sA =         (ks*2 + (lane>>5))*2064 + (lane&31)*16;
      const int sW = 16512 + (ks*2 + (lane>>5))*4112 + (lane&31)*16;
      bf16x8 aH0 = *(const bf16x8*)(smem +        sA + (wm*64    )*16);
      bf16x8 aH1 = *(const bf16x8*)(smem +        sA + (wm*64+32 )*16);
      bf16x8 aL0 = *(const bf16x8*)(smem + 8256 + sA + (wm*64    )*16);
      bf16x8 aL1 = *(const bf16x8*)(smem + 8256 + sA + (wm*64+32 )*16);
      bf16x8 bH0 = *(const bf16x8*)(smem +         sW + (wn*64    )*16);
      bf16x8 bH1 = *(const bf16x8*)(smem +         sW + (wn*64+32 )*16);
      bf16x8 bL0 = *(const bf16x8*)(smem + 16448 + sW + (wn*64    )*16);
      bf16x8 bL1 = *(const bf16x8*)(smem + 16448 + sW + (wn*64+32 )*16);
      acc[0][0] = MFMA32(aH0,bH0,acc[0][0],0,0,0);
      acc[0][0] = MFMA32(aH0,bL0,acc[0][0],0,0,0);
      acc[0][0] = MFMA32(aL0,bH0,acc[0][0],0,0,0);
      acc[0][1] = MFMA32(aH0,bH1,acc[0][1],0,0,0);
      acc[0][1] = MFMA32(aH0,bL1,acc[0][1],0,0,0);
      acc[0][1] = MFMA32(aL0,bH1,acc[0][1],0,0,0);
      acc[1][0] = MFMA32(aH1,bH0,acc[1][0],0,0,0);
      acc[1][0] = MFMA32(aH1,bL0,acc[1][0],0,0,0);
      acc[1][0] = MFMA32(aL1,bH0,acc[1][0],0,0,0);
      acc[1][1] = MFMA32(aH1,bH1,acc[1][1],0,0,0);
      acc[1][1] = MFMA32(aH1,bL1,acc[1][1],0,0,0);
      acc[1][1] = MFMA32(aL1,bH1,acc[1][1],0,0,0);
    }
  }

  // epilogue: +bias; fp32 or bf16 stores depending on output
#pragma unroll
  for (int fn = 0; fn < 2; ++fn) {
    const int col = wn*64 + fn*32 + (lane&31);
    float bval = bias[col];
#pragma unroll
    for (int fm = 0; fm < 2; ++fm) {
      int rbase = bm + wm*64 + fm*32 + 4*(lane>>5);
#pragma unroll
      for (int r = 0; r < 16; ++r) {
        int row = rbase + (r&3) + 8*(r>>2);
        if (row < M) {
          float v = acc[fm][fn][r] + bval;
          if (bf16out) Ch[(size_t)row*256 + col] = (__bf16)v;
          else         Cf[(size_t)row*256 + col] = v;
        }
      }
    }
  }
}

// ---------------------------------------------------------------------------
// Per-node attention projections (hs now bf16).
// ---------------------------------------------------------------------------
__global__ __launch_bounds__(256) void attn_vec_kernel(
    const __bf16* __restrict__ hs0, const __bf16* __restrict__ hs1,
    const float* __restrict__ hd,
    const float* __restrict__ srcA_W, const float* __restrict__ srcA_b,
    const float* __restrict__ dstA_W, const float* __restrict__ dstA_b,
    float* __restrict__ as0, float* __restrict__ as1,
    float* __restrict__ ad0, float* __restrict__ ad1, int N)
{
  int n = blockIdx.x*4 + (threadIdx.x >> 6);
  if (n >= N) return;
  int lane = threadIdx.x & 63;
  int d0 = lane << 2;
  const float4* Ws = (const float4*)srcA_W;
  const float4* Wd = (const float4*)dstA_W;
  bf16x4 t0 = ((const bf16x4*)hs0)[(size_t)n*64 + lane];
  bf16x4 t1 = ((const bf16x4*)hs1)[(size_t)n*64 + lane];
  float4 r0 = make_float4((float)t0[0],(float)t0[1],(float)t0[2],(float)t0[3]);
  float4 r1 = make_float4((float)t1[0],(float)t1[1],(float)t1[2],(float)t1[3]);
  float4 rd = ((const float4*)hd )[(size_t)n*64 + lane];
  float4 p0 = make_float4(0,0,0,0), p1 = make_float4(0,0,0,0);
  float4 q0 = make_float4(0,0,0,0), q1 = make_float4(0,0,0,0);
  float4 w;
  w = Ws[d0+0]; ACC4(p0, r0.x, w);
  w = Ws[d0+1]; ACC4(p0, r0.y, w);
  w = Ws[d0+2]; ACC4(p0, r0.z, w);
  w = Ws[d0+3]; ACC4(p0, r0.w, w);
  w = Ws[256+d0+0]; ACC4(p1, r1.x, w);
  w = Ws[256+d0+1]; ACC4(p1, r1.y, w);
  w = Ws[256+d0+2]; ACC4(p1, r1.z, w);
  w = Ws[256+d0+3]; ACC4(p1, r1.w, w);
  w = Wd[d0+0]; ACC4(q0, rd.x, w);
  w = Wd[d0+1]; ACC4(q0, rd.y, w);
  w = Wd[d0+2]; ACC4(q0, rd.z, w);
  w = Wd[d0+3]; ACC4(q0, rd.w, w);
  w = Wd[256+d0+0]; ACC4(q1, rd.x, w);
  w = Wd[256+d0+1]; ACC4(q1, rd.y, w);
  w = Wd[256+d0+2]; ACC4(q1, rd.z, w);
  w = Wd[256+d0+3]; ACC4(q1, rd.w, w);
  p0 = wred_sum4(p0); p1 = wred_sum4(p1); q0 = wred_sum4(q0); q1 = wred_sum4(q1);
  if (lane == 0) {
    float4 b;
    b = *(const float4*)(srcA_b + 0);
    ((float4*)as0)[n] = make_float4(p0.x+b.x, p0.y+b.y, p0.z+b.z, p0.w+b.w);
    b = *(const float4*)(srcA_b + 4);
    ((float4*)as1)[n] = make_float4(p1.x+b.x, p1.y+b.y, p1.z+b.z, p1.w+b.w);
    b = *(const float4*)(dstA_b + 0);
    ((float4*)ad0)[n] = make_float4(q0.x+b.x, q0.y+b.y, q0.z+b.z, q0.w+b.w);
    b = *(const float4*)(dstA_b + 4);
    ((float4*)ad1)[n] = make_float4(q1.x+b.x, q1.y+b.y, q1.z+b.z, q1.w+b.w);
  }
}

// rel attention (node-invariant), pre-scaled by (1-ALPHA)=0.5
__global__ void rel_kernel(const float* __restrict__ rel_emb, const float* __restrict__ relA_W,
                           const float* __restrict__ relA_b, float* __restrict__ rel_out)
{
  int t = threadIdx.x;
  if (t < 8) {
    int r = t >> 2, h = t & 3;
    float s = relA_b[r*4+h];
    for (int d = 0; d < 256; ++d)
      s = fmaf(rel_emb[r*256+d], relA_W[(size_t)(r*256+d)*4+h], s);
    s = lrelu(s);
    float other = __shfl_xor(s, 4);
    float mm = fmaxf(s, other);
    float e  = expf(s - mm), eo = expf(other - mm);
    rel_out[r*4+h] = 0.5f * e / (e + eo);
  }
}

// ---------------------------------------------------------------------------
// CSR build helpers
// ---------------------------------------------------------------------------
__global__ void zero_int(int* p, int n){
  int i = blockIdx.x*blockDim.x + threadIdx.x;
  if (i < n) p[i] = 0;
}

__global__ void hist_kernel(const int* __restrict__ dst0, const int* __restrict__ dst1,
                            int* c0, int* c1, int E){
  int e = blockIdx.x*256 + threadIdx.x;
  if (e < E) { atomicAdd(&c0[dst0[e]], 1); atomicAdd(&c1[dst1[e]], 1); }
}

__global__ __launch_bounds__(1024) void scan1(const int* __restrict__ cnt0, const int* __restrict__ cnt1,
                                              int* __restrict__ rp0, int* __restrict__ rp1,
                                              int* __restrict__ part0, int* __restrict__ part1, int n){
  const int* cnt = blockIdx.y ? cnt1 : cnt0;
  int* excl = blockIdx.y ? rp1 : rp0;
  int* part = blockIdx.y ? part1 : part0;
  __shared__ int sm[1024];
  int tid = threadIdx.x;
  int gid = blockIdx.x*1024 + tid;
  int v = (gid < n) ? cnt[gid] : 0;
  sm[tid] = v; __syncthreads();
  for (int off = 1; off < 1024; off <<= 1){
    int t = sm[tid];
    if (tid >= off) t += sm[tid-off];
    __syncthreads();
    sm[tid] = t; __syncthreads();
  }
  if (gid < n) excl[gid] = sm[tid] - v;
  if (tid == 1023) part[blockIdx.x] = sm[1023];
}

__global__ void scan2(int* part0, int* part1, int nchunk, int* tot0, int* tot1){
  if (threadIdx.x == 0 && blockIdx.x == 0){
    int run = 0;
    for (int i = 0; i < nchunk; ++i){ int t = part0[i]; part0[i] = run; run += t; }
    *tot0 = run;
    run = 0;
    for (int i = 0; i < nchunk; ++i){ int t = part1[i]; part1[i] = run; run += t; }
    *tot1 = run;
  }
}

__global__ __launch_bounds__(1024) void scan3(int* __restrict__ rp0, int* __restrict__ rp1,
                                              int* __restrict__ cur0, int* __restrict__ cur1,
                                              const int* __restrict__ part0, const int* __restrict__ part1, int n){
  int* rp  = blockIdx.y ? rp1 : rp0;
  int* cur = blockIdx.y ? cur1 : cur0;
  const int* part = blockIdx.y ? part1 : part0;
  int gid = blockIdx.x*1024 + threadIdx.x;
  if (gid < n){ int v = rp[gid] + part[blockIdx.x]; rp[gid] = v; cur[gid] = v; }
}

__global__ void scatter_kernel(const int* __restrict__ src0, const int* __restrict__ dst0,
                               int* cur0, int* __restrict__ csr0,
                               const int* __restrict__ src1, const int* __restrict__ dst1,
                               int* cur1, int* __restrict__ csr1, int E){
  int e = blockIdx.x*256 + threadIdx.x;
  if (e < E){
    int p = atomicAdd(&cur0[dst0[e]], 1); csr0[p] = src0[e];
    p = atomicAdd(&cur1[dst1[e]], 1); csr1[p] = src1[e];
  }
}

// ---------------------------------------------------------------------------
// Fused aggregation v3: one wave per (node,relation); bf16 hs gather (8B/lane)
// accumulated in fp32; single pass per edge; LDS exchange; fusion epilogue.
// ---------------------------------------------------------------------------
__device__ __forceinline__ void sm2(float s0, float s1, float r0, float r1, float& o0, float& o1){
  float mm = fmaxf(s0, s1);
  float e0 = expf(s0-mm), e1 = expf(s1-mm);
  float inv = 1.f/(e0+e1);
  o0 = fmaf(0.5f*e0, inv, r0);
  o1 = fmaf(0.5f*e1, inv, r1);
}

__global__ __launch_bounds__(256) void aggregate_fused2(
    const int* __restrict__ rp0, const int* __restrict__ csr0,
    const float* __restrict__ as0, const float* __restrict__ ad0,
    const __bf16* __restrict__ hs0,
    const int* __restrict__ rp1, const int* __restrict__ csr1,
    const float* __restrict__ as1, const float* __restrict__ ad1,
    const __bf16* __restrict__ hs1,
    float* __restrict__ hd_io, const float* __restrict__ hA,
    const float* __restrict__ semS_W, const float* __restrict__ semS_b,
    const float* __restrict__ semD_W, const float* __restrict__ semD_b,
    const float* __restrict__ relw, int N)
{
  __shared__ float4 a1_lds[2][64];
  const int tid    = threadIdx.x;
  const int lane   = tid & 63;
  const int wid    = tid >> 6;
  const int locn   = wid >> 1;       // 0/1: node within block
  const int rel    = wid & 1;        // 0/1: relation
  const int n      = blockIdx.x*2 + locn;
  const int h      = lane >> 4;
  const bool active = (n < N);

  float4 acc = make_float4(0.f,0.f,0.f,0.f);
  if (active) {
    const int*    rp  = rel ? rp1  : rp0;
    const int*    csr = rel ? csr1 : csr0;
    const float*  as  = rel ? as1  : as0;
    const float*  ad  = rel ? ad1  : ad0;
    const __bf16* hs  = rel ? hs1  : hs0;
    int start = rp[n];
    int cnt   = rp[n+1] - start;
    if (cnt > 0) {
      float adh = ad[(size_t)n*4 + h];
      const bf16x4* hsv = (const bf16x4*)hs;
      float ssum = 0.f;
      int i = 0;
      for (; i+4 <= cnt; i += 4) {
        int s0 = csr[start+i], s1 = csr[start+i+1], s2 = csr[start+i+2], s3 = csr[start+i+3];
        float w0 = __expf(lrelu(as[(size_t)s0*4+h] + adh));
        float w1 = __expf(lrelu(as[(size_t)s1*4+h] + adh));
        float w2 = __expf(lrelu(as[(size_t)s2*4+h] + adh));
        float w3 = __expf(lrelu(as[(size_t)s3*4+h] + adh));
        bf16x4 v0 = hsv[(size_t)s0*64 + lane];
        bf16x4 v1 = hsv[(size_t)s1*64 + lane];
        bf16x4 v2 = hsv[(size_t)s2*64 + lane];
        bf16x4 v3 = hsv[(size_t)s3*64 + lane];
        acc.x = fmaf((float)v0[0],w0,acc.x); acc.y = fmaf((float)v0[1],w0,acc.y);
        acc.z = fmaf((float)v0[2],w0,acc.z); acc.w = fmaf((float)v0[3],w0,acc.w);
        acc.x = fmaf((float)v1[0],w1,acc.x); acc.y = fmaf((float)v1[1],w1,acc.y);
        acc.z = fmaf((float)v1[2],w1,acc.z); acc.w = fmaf((float)v1[3],w1,acc.w);
        acc.x = fmaf((float)v2[0],w2,acc.x); acc.y = fmaf((float)v2[1],w2,acc.y);
        acc.z = fmaf((float)v2[2],w2,acc.z); acc.w = fmaf((float)v2[3],w2,acc.w);
        acc.x = fmaf((float)v3[0],w3,acc.x); acc.y = fmaf((float)v3[1],w3,acc.y);
        acc.z = fmaf((float)v3[2],w3,acc.z); acc.w = fmaf((float)v3[3],w3,acc.w);
        ssum += w0 + w1 + w2 + w3;
      }
      for (; i < cnt; ++i) {
        int s = csr[start+i];
        float wv = __expf(lrelu(as[(size_t)s*4+h] + adh));
        bf16x4 v = hsv[(size_t)s*64 + lane];
        acc.x = fmaf((float)v[0],wv,acc.x); acc.y = fmaf((float)v[1],wv,acc.y);
        acc.z = fmaf((float)v[2],wv,acc.z); acc.w = fmaf((float)v[3],wv,acc.w);
        ssum += wv;
      }
      float inv = 1.f / ssum;
      acc.x *= inv; acc.y *= inv; acc.z *= inv; acc.w *= inv;
    }
  }
  if (rel == 1) a1_lds[locn][lane] = acc;
  __syncthreads();
  if (rel == 1 || !active) return;

  // ---- fusion epilogue (rel0 wave of each node) ----
  float4 a0 = acc;
  float4 a1 = a1_lds[locn][lane];
  int d0 = lane << 2;
  float4 ad = ((float4*)hd_io)[(size_t)n*64 + lane];   // z_dst row
  float4 ha = ((const float4*)hA)[(size_t)n*64 + lane];
  float nz0 = wred_sum(a0.x*a0.x + a0.y*a0.y + a0.z*a0.z + a0.w*a0.w);
  float nz1 = wred_sum(a1.x*a1.x + a1.y*a1.y + a1.z*a1.z + a1.w*a1.w);
  float nzd = wred_sum(ad.x*ad.x + ad.y*ad.y + ad.z*ad.z + ad.w*ad.w);
  float i0  = 1.f / fmaxf(sqrtf(nz0), 1e-9f);
  float i1  = 1.f / fmaxf(sqrtf(nz1), 1e-9f);
  float idn = 1.f / fmaxf(sqrtf(nzd), 1e-9f);
  const float4* WS = (const float4*)semS_W;
  const float4* WD = (const float4*)semD_W;
  float4 p0 = make_float4(0,0,0,0), p1 = make_float4(0,0,0,0);
  float4 q0 = make_float4(0,0,0,0), q1 = make_float4(0,0,0,0);
  float4 w;
  w = WS[d0+0]; ACC4(p0, a0.x, w);
  w = WS[d0+1]; ACC4(p0, a0.y, w);
  w = WS[d0+2]; ACC4(p0, a0.z, w);
  w = WS[d0+3]; ACC4(p0, a0.w, w);
  w = WS[256+d0+0]; ACC4(p1, a1.x, w);
  w = WS[256+d0+1]; ACC4(p1, a1.y, w);
  w = WS[256+d0+2]; ACC4(p1, a1.z, w);
  w = WS[256+d0+3]; ACC4(p1, a1.w, w);
  w = WD[d0+0]; ACC4(q0, ad.x, w);
  w = WD[d0+1]; ACC4(q0, ad.y, w);
  w = WD[d0+2]; ACC4(q0, ad.z, w);
  w = WD[d0+3]; ACC4(q0, ad.w, w);
  w = WD[256+d0+0]; ACC4(q1, ad.x, w);
  w = WD[256+d0+1]; ACC4(q1, ad.y, w);
  w = WD[256+d0+2]; ACC4(q1, ad.z, w);
  w = WD[256+d0+3]; ACC4(q1, ad.w, w);
  p0 = wred_sum4(p0); p1 = wred_sum4(p1); q0 = wred_sum4(q0); q1 = wred_sum4(q1);
  float4 sb0 = *(const float4*)(semS_b + 0);
  float4 sb1 = *(const float4*)(semS_b + 4);
  float4 db0 = *(const float4*)(semD_b + 0);
  float4 db1 = *(const float4*)(semD_b + 4);
  float4 s0, s1;
  s0.x = lrelu(p0.x*i0 + sb0.x + q0.x*idn + db0.x);
  s0.y = lrelu(p0.y*i0 + sb0.y + q0.y*idn + db0.y);
  s0.z = lrelu(p0.z*i0 + sb0.z + q0.z*idn + db0.z);
  s0.w = lrelu(p0.w*i0 + sb0.w + q0.w*idn + db0.w);
  s1.x = lrelu(p1.x*i1 + sb1.x + q1.x*idn + db1.x);
  s1.y = lrelu(p1.y*i1 + sb1.y + q1.y*idn + db1.y);
  s1.z = lrelu(p1.z*i1 + sb1.z + q1.z*idn + db1.z);
  s1.w = lrelu(p1.w*i1 + sb1.w + q1.w*idn + db1.w);
  float4 at0, at1;
  sm2(s0.x, s1.x, relw[0], relw[4], at0.x, at1.x);
  sm2(s0.y, s1.y, relw[1], relw[5], at0.y, at1.y);
  sm2(s0.z, s1.z, relw[2], relw[6], at0.z, at1.z);
  sm2(s0.w, s1.w, relw[3], relw[7], at0.w, at1.w);
  float w0 = h==0 ? at0.x : h==1 ? at0.y : h==2 ? at0.z : at0.w;
  float w1 = h==0 ? at1.x : h==1 ? at1.y : h==2 ? at1.z : at1.w;
  float4 x;
  x.x = fmaf(a0.x, w0, fmaf(a1.x, w1, ha.x));
  x.y = fmaf(a0.y, w0, fmaf(a1.y, w1, ha.y));
  x.z = fmaf(a0.z, w0, fmaf(a1.z, w1, ha.z));
  x.w = fmaf(a0.w, w0, fmaf(a1.w, w1, ha.w));
  float4 g;
  g.x = gelu_exact(x.x); g.y = gelu_exact(x.y); g.z = gelu_exact(x.z); g.w = gelu_exact(x.w);
  float ng = wred_sum(g.x*g.x + g.y*g.y + g.z*g.z + g.w*g.w);
  float inv = 1.f / fmaxf(sqrtf(ng), 1e-9f);
  g.x *= inv; g.y *= inv; g.z *= inv; g.w *= inv;
  ((float4*)hd_io)[(size_t)n*64 + lane] = g;
}

// Node type B fallback: out_B = normalize(gelu(nb + h_B)); nb lives in outB region.
__global__ __launch_bounds__(256) void fusionB_kernel(float* __restrict__ outB,
                                                      const float* __restrict__ hB, int N)
{
  int n = blockIdx.x*4 + (threadIdx.x >> 6);
  if (n >= N) return;
  int lane = threadIdx.x & 63;
  float4 x = ((float4*)outB)[(size_t)n*64 + lane];
  float4 b = ((const float4*)hB)[(size_t)n*64 + lane];
  x.x += b.x; x.y += b.y; x.z += b.z; x.w += b.w;
  float4 g;
  g.x = gelu_exact(x.x); g.y = gelu_exact(x.y); g.z = gelu_exact(x.z); g.w = gelu_exact(x.w);
  float ng = wred_sum(g.x*g.x + g.y*g.y + g.z*g.z + g.w*g.w);
  float inv = 1.f / fmaxf(sqrtf(ng), 1e-9f);
  g.x *= inv; g.y *= inv; g.z *= inv; g.w *= inv;
  ((float4*)outB)[(size_t)n*64 + lane] = g;
}

// ---------------------------------------------------------------------------
extern "C" void kernel_launch(void* const* d_in, const int* in_sizes, int n_in,
                              void* d_out, int out_size, void* d_ws, size_t ws_size,
                              hipStream_t stream)
{
  const float* hA     = (const float*)d_in[0];
  const float* hB     = (const float*)d_in[1];
  const int*   src0   = (const int*)d_in[2];
  const int*   dst0   = (const int*)d_in[3];
  const int*   src1   = (const int*)d_in[4];
  const int*   dst1   = (const int*)d_in[5];
  const float* node_W = (const float*)d_in[6];
  const float* node_b = (const float*)d_in[7];
  const float* edge_W = (const float*)d_in[8];
  const float* edge_b = (const float*)d_in[9];
  const float* srcA_W = (const float*)d_in[10];
  const float* srcA_b = (const float*)d_in[11];
  const float* dstA_W = (const float*)d_in[12];
  const float* dstA_b = (const float*)d_in[13];
  const float* semS_W = (const float*)d_in[14];
  const float* semS_b = (const float*)d_in[15];
  const float* semD_W = (const float*)d_in[16];
  const float* semD_b = (const float*)d_in[17];
  const float* relA_W = (const float*)d_in[18];
  const float* relA_b = (const float*)d_in[19];
  const float* rel_emb= (const float*)d_in[20];

  const int N = in_sizes[0] / D;
  const int E = in_sizes[2];

  float* out  = (float*)d_out;
  float* outA = out;                    // scratch for hd (=z_dst), then final out_A
  float* outB = out + (size_t)N*D;      // scratch for nb, then final out_B

  float* w = (float*)d_ws;
  __bf16* hs0 = (__bf16*)w; w += (size_t)N*D/2;   // bf16, N*D*2 bytes
  __bf16* hs1 = (__bf16*)w; w += (size_t)N*D/2;
  float* as0  = w; w += (size_t)N*HN;
  float* as1  = w; w += (size_t)N*HN;
  float* ad0  = w; w += (size_t)N*HN;
  float* ad1  = w; w += (size_t)N*HN;
  float* relw = w; w += 16;
  __bf16* WtHi = (__bf16*)w; w += 131072;   // 4 mats * 65536 bf16 = 512KB
  __bf16* WtLo = (__bf16*)w; w += 131072;
  int* ip   = (int*)w;
  int* cnt0 = ip; ip += N;
  int* cnt1 = ip; ip += N;
  int* rp0  = ip; ip += N+1;
  int* rp1  = ip; ip += N+1;
  int* cur0 = ip; ip += N;
  int* cur1 = ip; ip += N;
  int* part0= ip; ip += 256;
  int* part1= ip; ip += 256;
  int* csr0 = ip; ip += E;
  int* csr1 = ip; ip += E;

  const int nwb = (N + 3) / 4;

  // weight transpose + bf16 hi/lo split (DMA-tile order)
  wt_setup<<<128, 256, 0, stream>>>(node_W, edge_W, WtHi, WtLo);

  // 4 GEMMs batched in one launch (grid.y selects matrix), BN=256 full width
  dim3 ggrid((N + 127)/128, 4);
  gemm_mfma4<<<ggrid, 512, 0, stream>>>(hA, hB, WtHi, WtLo, node_b, edge_b,
                                        outA, hs0, hs1, outB, N);

  attn_vec_kernel<<<nwb, 256, 0, stream>>>(hs0, hs1, outA, srcA_W, srcA_b, dstA_W, dstA_b,
                                           as0, as1, ad0, ad1, N);
  rel_kernel<<<1, 64, 0, stream>>>(rel_emb, relA_W, relA_b, relw);

  // CSR build for both relations
  zero_int<<<(2*N + 255)/256, 256, 0, stream>>>(cnt0, 2*N);
  hist_kernel<<<(E + 255)/256, 256, 0, stream>>>(dst0, dst1, cnt0, cnt1, E);
  const int nchunk = (N + 1023)/1024;
  dim3 sgrid(nchunk, 2);
  scan1<<<sgrid, 1024, 0, stream>>>(cnt0, cnt1, rp0, rp1, part0, part1, N);
  scan2<<<1, 64, 0, stream>>>(part0, part1, nchunk, rp0 + N, rp1 + N);
  scan3<<<sgrid, 1024, 0, stream>>>(rp0, rp1, cur0, cur1, part0, part1, N);
  scatter_kernel<<<(E + 255)/256, 256, 0, stream>>>(src0, dst0, cur0, csr0,
                                                    src1, dst1, cur1, csr1, E);

  // fused aggregation v3: wave per (node, relation), bf16 gathers
  aggregate_fused2<<<(N + 1)/2, 256, 0, stream>>>(rp0, csr0, as0, ad0, hs0,
                                                  rp1, csr1, as1, ad1, hs1,
                                                  outA, hA, semS_W, semS_b, semD_W, semD_b,
                                                  relw, N);

  fusionB_kernel<<<nwb, 256, 0, stream>>>(outB, hB, N);
}